// Round 19
// baseline (3846.159 us; speedup 1.0000x reference)
//
#include <hip/hip_runtime.h>

typedef unsigned long long u64;
typedef unsigned int u32;

#define HW 32400
#define IMG 180
#define NTASK 6

__constant__ int c_nc[NTASK] = {1, 2, 2, 1, 2, 2};

// async global->LDS, 16B per lane, wave-uniform LDS base
#define GLL16(SRC, DST)                                                      \
    __builtin_amdgcn_global_load_lds(                                        \
        (const __attribute__((address_space(1))) unsigned int*)(SRC),        \
        (__attribute__((address_space(3))) unsigned int*)(DST), 16, 0, 0)

// ---------------------------------------------------------------------------
// zero page init (64 floats) — OOB staging lanes read from here
// ---------------------------------------------------------------------------
__global__ void zp_init_kernel(float* zp)
{
    zp[threadIdx.x] = 0.f;
}

// ---------------------------------------------------------------------------
// 3x3 stride-1 pad-1 conv + ReLU, v19 = v18 (conflicts -> 0, 1766us) with
// 2px x 16oc per thread (same 32 acc) to HALVE input LDS reads:
// per (ic,dy): 6 b32 reads feed 96 FMAs (v18: 12/96). Thread (xg=tid&15,
// y=tid>>4) owns px (y, xg) and (y, xg+16), all 16 oc. Read addr =
// 40(y+dy) + xg+3+dx (+16) -> bank (8*(lane>>4) + (lane&15) + c) mod 32 ->
// exactly 2 lanes/bank (free). Weight reads become 4 b128/tap broadcasts
// (1 LDS cyc each), interleaved per-quarter to cap liveness at 4 regs.
// Staging/layout/barriers byte-identical to v18 (GLL16 async, zero page,
// 3-ic chunks, double buffer, one barrier/chunk). grid.x=36*n_ocb, XCD-swz.
// ---------------------------------------------------------------------------
__device__ __forceinline__ void stage_in_async3(
    const float* __restrict__ in, const float* __restrict__ zp,
    float* lds_buf, int ic0, int IC, int ty0, int tx0, int tid)
{
    int lane = tid & 63;
    int wv = tid >> 6;          // 0..7
#pragma unroll
    for (int kk = 0; kk < 2; ++kk) {
        int k = wv + kk * 8;    // 0..15; 3*1360 = 4080 words = 16 issues
        int e = k * 256 + lane * 4;       // word index, mult of 4
        if (e < 4080) {
            int ic = e / 1360;            // 0..2
            int r2 = e - ic * 1360;
            int rr = r2 / 40;
            int cc = r2 - rr * 40;        // mult of 4
            int gy = ty0 - 1 + rr;
            int gx0 = tx0 - 4 + cc;       // 16B-aligned source col
            const float* src = zp;
            if (ic0 + ic < IC && (unsigned)gy < 180u && (unsigned)gx0 < 180u)
                src = in + (size_t)(ic0 + ic) * HW + (size_t)(gy * IMG + gx0);
            GLL16(src, lds_buf + e);
        }
    }
}

__global__ __launch_bounds__(512) void conv3x3_relu_v19(
    const float* __restrict__ in, const float* __restrict__ wgt,
    const float* __restrict__ bias, float* __restrict__ out,
    const float* __restrict__ zp, int IC, int n_ocb)
{
    __shared__ float s_in[2][4080];   // 3 ic x 34 rows x 40 cols
    __shared__ float s_w[2][432];     // [ic][tap][oc] flat (3*9*16)

    int per = gridDim.x >> 3;
    int g = (blockIdx.x & 7) * per + (blockIdx.x >> 3);
    int sp = g / n_ocb;
    int ocb = g - sp * n_ocb;
    int oc0 = ocb * 16;
    int ty0 = (sp / 6) * 32, tx0 = (sp % 6) * 32;

    int tid = threadIdx.x;
    int xg = tid & 15, y = tid >> 4;   // 16 x-groups x 32 rows

    const int NC = (IC + 2) / 3;   // last chunk padded

    // weight-load thread mapping (tid < 432): wq = tid>>4 in 0..26
    int wq = tid >> 4;
    int w_ic = wq / 9, w_tap = wq - w_ic * 9, w_oc = tid & 15;
    bool w_on = tid < 432;

    float acc[2][16];
#pragma unroll
    for (int p = 0; p < 2; ++p)
#pragma unroll
        for (int o = 0; o < 16; ++o) acc[p][o] = 0.f;

    // ---- prologue: stage chunk 0 into buffer 0 ----
    {
        float wA = 0.f;
        if (w_on && w_ic < IC)
            wA = wgt[((size_t)(oc0 + w_oc) * IC + w_ic) * 9 + w_tap];
        stage_in_async3(in, zp, &s_in[0][0], 0, IC, ty0, tx0, tid);
        if (w_on) s_w[0][tid] = wA;
    }
    __syncthreads();

    for (int c = 0; c < NC; ++c) {
        int cur = c & 1;

        // ---- prefetch chunk c+1 (weights->regs, async inputs,
        //      weights->LDS) ----
        if (c + 1 < NC) {
            int nic0 = (c + 1) * 3;
            float wN = 0.f;
            if (w_on && nic0 + w_ic < IC)
                wN = wgt[((size_t)(oc0 + w_oc) * IC + nic0 + w_ic) * 9 + w_tap];
            stage_in_async3(in, zp, &s_in[cur ^ 1][0], nic0, IC, ty0, tx0, tid);
            if (w_on) s_w[cur ^ 1][tid] = wN;
        }

        // ---- compute chunk c (3 ic); 2 strided px x 16 oc ----
        {
            const float* sbuf = &s_in[cur][0];
            const float* swb = &s_w[cur][0];
#pragma unroll
            for (int ic = 0; ic < 3; ++ic) {
#pragma unroll
                for (int dy = 0; dy < 3; ++dy) {
                    const float* rowb =
                        sbuf + ic * 1360 + (y + dy) * 40 + xg + 3;
                    float va[3], vb[3];
#pragma unroll
                    for (int i = 0; i < 3; ++i) {
                        va[i] = rowb[i];
                        vb[i] = rowb[16 + i];
                    }
#pragma unroll
                    for (int dx = 0; dx < 3; ++dx) {
                        const float* wpp =
                            swb + (ic * 9 + dy * 3 + dx) * 16;
                        float a = va[dx], b = vb[dx];
#pragma unroll
                        for (int q = 0; q < 4; ++q) {
                            float4 w = *(const float4*)(wpp + 4 * q);
                            acc[0][4 * q + 0] = fmaf(a, w.x, acc[0][4 * q + 0]);
                            acc[0][4 * q + 1] = fmaf(a, w.y, acc[0][4 * q + 1]);
                            acc[0][4 * q + 2] = fmaf(a, w.z, acc[0][4 * q + 2]);
                            acc[0][4 * q + 3] = fmaf(a, w.w, acc[0][4 * q + 3]);
                            acc[1][4 * q + 0] = fmaf(b, w.x, acc[1][4 * q + 0]);
                            acc[1][4 * q + 1] = fmaf(b, w.y, acc[1][4 * q + 1]);
                            acc[1][4 * q + 2] = fmaf(b, w.z, acc[1][4 * q + 2]);
                            acc[1][4 * q + 3] = fmaf(b, w.w, acc[1][4 * q + 3]);
                        }
                    }
                }
            }
        }
        __syncthreads();   // drains async loads (issued ~full compute ago)
    }

    // ---- epilogue: bias + relu + strided scalar stores ----
    int gy = ty0 + y;
    if (gy < IMG) {
#pragma unroll
        for (int p = 0; p < 2; ++p) {
            int gxp = tx0 + xg + 16 * p;
            if (gxp < IMG) {
#pragma unroll
                for (int o = 0; o < 16; ++o) {
                    float r = acc[p][o] + bias[oc0 + o];
                    r = r > 0.f ? r : 0.f;
                    out[(size_t)(oc0 + o) * HW + gy * IMG + gxp] = r;
                }
            }
        }
    }
}

// ---------------------------------------------------------------------------
// 3x3 stride-2 pad-1 conv + ReLU, v2: [128][180][180] -> [256][90][90]
// ---------------------------------------------------------------------------
__global__ __launch_bounds__(256) void conv3x3s2_relu_v2(
    const float* __restrict__ in, const float* __restrict__ wgt,
    const float* __restrict__ bias, float* __restrict__ out)
{
    __shared__ float s_in[2][31][34];
    __shared__ float s_w[2][9][16];

    int sp = blockIdx.x; int ocb = blockIdx.y;
    int oty0 = (sp / 6) * 15, otx0 = (sp % 6) * 15;
    int iy0 = 2 * oty0 - 1, ix0 = 2 * otx0 - 1;
    int tid = threadIdx.x;
    int tx = tid & 15, ty = tid >> 4;
    bool active = (tx < 15) && (ty < 15);

    float acc[16];
#pragma unroll
    for (int o = 0; o < 16; ++o) acc[o] = 0.f;

    for (int ic0 = 0; ic0 < 128; ic0 += 2) {
        __syncthreads();
        for (int e = tid; e < 2 * 31 * 31; e += 256) {
            int ic = e / 961; int rem = e - ic * 961;
            int rr = rem / 31; int cc = rem - rr * 31;
            int gy = iy0 + rr, gx = ix0 + cc;
            float v = 0.f;
            if ((unsigned)gy < 180u && (unsigned)gx < 180u)
                v = in[(size_t)(ic0 + ic) * HW + gy * IMG + gx];
            s_in[ic][rr][cc] = v;
        }
        for (int e = tid; e < 288; e += 256) {
            int oc = e & 15; int tap = (e >> 4) % 9; int ic = e / 144;
            s_w[ic][tap][oc] =
                wgt[((size_t)(ocb * 16 + oc) * 128 + ic0 + ic) * 9 + tap];
        }
        __syncthreads();
        if (!active) continue;
#pragma unroll
        for (int ic = 0; ic < 2; ++ic) {
#pragma unroll
            for (int tap = 0; tap < 9; ++tap) {
                int dy = tap / 3, dx = tap - dy * 3;
                float v = s_in[ic][2 * ty + dy][2 * tx + dx];
                float4 w0 = *(const float4*)&s_w[ic][tap][0];
                float4 w1 = *(const float4*)&s_w[ic][tap][4];
                float4 w2 = *(const float4*)&s_w[ic][tap][8];
                float4 w3 = *(const float4*)&s_w[ic][tap][12];
                float wv[16] = {w0.x, w0.y, w0.z, w0.w, w1.x, w1.y, w1.z, w1.w,
                                w2.x, w2.y, w2.z, w2.w, w3.x, w3.y, w3.z, w3.w};
#pragma unroll
                for (int o = 0; o < 16; ++o) acc[o] = fmaf(v, wv[o], acc[o]);
            }
        }
    }
    if (active) {
        int yy = oty0 + ty, xx = otx0 + tx;
#pragma unroll
        for (int o = 0; o < 16; ++o) {
            float r = acc[o] + bias[ocb * 16 + o];
            out[(size_t)(ocb * 16 + o) * 8100 + yy * 90 + xx] =
                r > 0.f ? r : 0.f;
        }
    }
}

// ---------------------------------------------------------------------------
// 1x1 conv 128->256 + ReLU (writes neck channels 0..255)
// ---------------------------------------------------------------------------
__global__ __launch_bounds__(256) void conv1x1_relu_kernel(
    const float* __restrict__ in, const float* __restrict__ w,
    const float* __restrict__ bias, float* __restrict__ out)
{
    __shared__ float s_x[8][256];
    __shared__ float s_w[8][16];
    int p0 = blockIdx.x * 256; int ocb = blockIdx.y;
    int tid = threadIdx.x;
    float acc[16];
#pragma unroll
    for (int o = 0; o < 16; ++o) acc[o] = 0.f;

    for (int ic0 = 0; ic0 < 128; ic0 += 8) {
        for (int e = tid; e < 2048; e += 256) {
            int ic = e >> 8; int p = e & 255;
            s_x[ic][p] = (p0 + p < HW) ? in[(size_t)(ic0 + ic) * HW + p0 + p] : 0.f;
        }
        for (int e = tid; e < 128; e += 256) {
            int ic = e >> 4; int oc = e & 15;
            s_w[ic][oc] = w[(size_t)(ocb * 16 + oc) * 128 + ic0 + ic];
        }
        __syncthreads();
#pragma unroll
        for (int ic = 0; ic < 8; ++ic) {
            float v = s_x[ic][tid];
            float4 w0 = *(const float4*)&s_w[ic][0];
            float4 w1 = *(const float4*)&s_w[ic][4];
            float4 w2 = *(const float4*)&s_w[ic][8];
            float4 w3 = *(const float4*)&s_w[ic][12];
            float wv[16] = {w0.x, w0.y, w0.z, w0.w, w1.x, w1.y, w1.z, w1.w,
                            w2.x, w2.y, w2.z, w2.w, w3.x, w3.y, w3.z, w3.w};
#pragma unroll
            for (int o = 0; o < 16; ++o) acc[o] = fmaf(v, wv[o], acc[o]);
        }
        __syncthreads();
    }
    int p = p0 + tid;
    if (p < HW) {
#pragma unroll
        for (int o = 0; o < 16; ++o) {
            float r = acc[o] + bias[ocb * 16 + o];
            out[(size_t)(ocb * 16 + o) * HW + p] = r > 0.f ? r : 0.f;
        }
    }
}

// ---------------------------------------------------------------------------
// 2x2 stride-2 transposed conv + ReLU: x1[256][90][90] -> neck ch 256..511
// ---------------------------------------------------------------------------
__global__ __launch_bounds__(256) void deconv2x2_relu_kernel(
    const float* __restrict__ in, const float* __restrict__ wgt,
    const float* __restrict__ bias, float* __restrict__ out)
{
    __shared__ float s_x[8][256];
    __shared__ float s_w[8][4][16];
    int p0 = blockIdx.x * 256; int ocb = blockIdx.y;
    int tid = threadIdx.x;
    float acc[4][16];
#pragma unroll
    for (int ab = 0; ab < 4; ++ab)
#pragma unroll
        for (int o = 0; o < 16; ++o) acc[ab][o] = 0.f;

    for (int ic0 = 0; ic0 < 256; ic0 += 8) {
        for (int e = tid; e < 2048; e += 256) {
            int ic = e >> 8; int p = e & 255;
            s_x[ic][p] = (p0 + p < 8100) ? in[(size_t)(ic0 + ic) * 8100 + p0 + p] : 0.f;
        }
        for (int e = tid; e < 512; e += 256) {
            int oc = e & 15; int ab = (e >> 4) & 3; int ic = e >> 6;
            s_w[ic][ab][oc] =
                wgt[((size_t)(ocb * 16 + oc) * 256 + ic0 + ic) * 4 + ab];
        }
        __syncthreads();
#pragma unroll
        for (int ic = 0; ic < 8; ++ic) {
            float v = s_x[ic][tid];
#pragma unroll
            for (int ab = 0; ab < 4; ++ab) {
                float4 w0 = *(const float4*)&s_w[ic][ab][0];
                float4 w1 = *(const float4*)&s_w[ic][ab][4];
                float4 w2 = *(const float4*)&s_w[ic][ab][8];
                float4 w3 = *(const float4*)&s_w[ic][ab][12];
                float wv[16] = {w0.x, w0.y, w0.z, w0.w, w1.x, w1.y, w1.z, w1.w,
                                w2.x, w2.y, w2.z, w2.w, w3.x, w3.y, w3.z, w3.w};
#pragma unroll
                for (int o = 0; o < 16; ++o)
                    acc[ab][o] = fmaf(v, wv[o], acc[ab][o]);
            }
        }
        __syncthreads();
    }
    int sp = p0 + tid;
    if (sp < 8100) {
        int sy = sp / 90, sx = sp - sy * 90;
#pragma unroll
        for (int ab = 0; ab < 4; ++ab) {
            int a = ab >> 1, bb = ab & 1;
            int Y = 2 * sy + a, X = 2 * sx + bb;
#pragma unroll
            for (int o = 0; o < 16; ++o) {
                float r = acc[ab][o] + bias[ocb * 16 + o];
                out[(size_t)(ocb * 16 + o) * HW + Y * IMG + X] = r > 0.f ? r : 0.f;
            }
        }
    }
}

// ---------------------------------------------------------------------------
// Per-pixel 1x1 heads (12 outputs from 64 ch) + sigmoid on hm channels.
// ---------------------------------------------------------------------------
__global__ __launch_bounds__(256) void heads_kernel(
    const float* __restrict__ sh,
    const float* __restrict__ w_hm, const float* __restrict__ b_hm,
    const float* __restrict__ w_reg, const float* __restrict__ b_reg,
    const float* __restrict__ w_hei, const float* __restrict__ b_hei,
    const float* __restrict__ w_dim, const float* __restrict__ b_dim,
    const float* __restrict__ w_rot, const float* __restrict__ b_rot,
    const float* __restrict__ w_vel, const float* __restrict__ b_vel,
    float* __restrict__ hm_sig, float* __restrict__ heads)
{
    __shared__ float s_w[64][12];
    __shared__ float s_b[12];
    int t = blockIdx.y;
    int tid = threadIdx.x;
    for (int e = tid; e < 768; e += 256) {
        int c = e / 12; int r = e - c * 12;
        float v;
        if (r < 2)       v = w_hm [(t * 2 + r) * 64 + c];
        else if (r < 4)  v = w_reg[(t * 2 + r - 2) * 64 + c];
        else if (r < 5)  v = w_hei[t * 64 + c];
        else if (r < 8)  v = w_dim[(t * 3 + r - 5) * 64 + c];
        else if (r < 10) v = w_rot[(t * 2 + r - 8) * 64 + c];
        else             v = w_vel[(t * 2 + r - 10) * 64 + c];
        s_w[c][r] = v;
    }
    if (tid < 12) {
        int r = tid; float v;
        if (r < 2)       v = b_hm [t * 2 + r];
        else if (r < 4)  v = b_reg[t * 2 + r - 2];
        else if (r < 5)  v = b_hei[t];
        else if (r < 8)  v = b_dim[t * 3 + r - 5];
        else if (r < 10) v = b_rot[t * 2 + r - 8];
        else             v = b_vel[t * 2 + r - 10];
        s_b[r] = v;
    }
    __syncthreads();
    int p = blockIdx.x * 256 + tid;
    if (p >= HW) return;
    float a[12];
#pragma unroll
    for (int r = 0; r < 12; ++r) a[r] = 0.f;
    const float* shp = sh + (size_t)t * 64 * HW + p;
    for (int c = 0; c < 64; ++c) {
        float x = shp[(size_t)c * HW];
        float4 w0 = *(const float4*)&s_w[c][0];
        float4 w1 = *(const float4*)&s_w[c][4];
        float4 w2 = *(const float4*)&s_w[c][8];
        float wv[12] = {w0.x, w0.y, w0.z, w0.w, w1.x, w1.y, w1.z, w1.w,
                        w2.x, w2.y, w2.z, w2.w};
#pragma unroll
        for (int r = 0; r < 12; ++r) a[r] = fmaf(x, wv[r], a[r]);
    }
#pragma unroll
    for (int r = 0; r < 12; ++r) a[r] += s_b[r];
    hm_sig[(size_t)(t * 2 + 0) * HW + p] = 1.f / (1.f + expf(-a[0]));
    hm_sig[(size_t)(t * 2 + 1) * HW + p] = 1.f / (1.f + expf(-a[1]));
#pragma unroll
    for (int r = 0; r < 10; ++r)
        heads[(size_t)(t * 10 + r) * HW + p] = a[2 + r];
}

// ---------------------------------------------------------------------------
// 3x3 max-pool NMS -> packed sort keys (score_bits<<32 | ~combined_idx)
// ---------------------------------------------------------------------------
__global__ __launch_bounds__(256) void nms_key_kernel(
    const float* __restrict__ hm_sig, u64* __restrict__ keys)
{
    int t = blockIdx.y;
    int i = blockIdx.x * 256 + threadIdx.x;   // < 65536
    int nc = c_nc[t];
    u64 key = 0;
    if (i < nc * HW) {
        int c = i / HW; int p = i - c * HW;
        int y = p / IMG; int x = p - y * IMG;
        const float* base = hm_sig + (size_t)(t * 2 + c) * HW;
        float s = base[p];
        float m = s;
#pragma unroll
        for (int dy = -1; dy <= 1; ++dy)
#pragma unroll
            for (int dx = -1; dx <= 1; ++dx) {
                int yy = y + dy, xx = x + dx;
                if ((unsigned)yy < 180u && (unsigned)xx < 180u)
                    m = fmaxf(m, base[yy * IMG + xx]);
            }
        float sm = (s == m) ? s : 0.f;
        key = ((u64)__float_as_uint(sm) << 32) | (u64)(u32)(~(u32)i);
    }
    keys[(size_t)t * 65536 + i] = key;
}

// ---------------------------------------------------------------------------
// Bitonic sort (descending) of N u64 keys in LDS, T threads.
// ---------------------------------------------------------------------------
template <int N, int T>
__device__ void bitonic_sort_desc(u64* s)
{
    const int tid = threadIdx.x;
    for (int k = 2; k <= N; k <<= 1) {
        for (int j = k >> 1; j > 0; j >>= 1) {
            __syncthreads();
            for (int idx = tid; idx < N / 2; idx += T) {
                int i = ((idx & ~(j - 1)) << 1) | (idx & (j - 1));
                int l = i | j;
                u64 a = s[i], b = s[l];
                bool sw = ((i & k) == 0) ? (a < b) : (a > b);
                if (sw) { s[i] = b; s[l] = a; }
            }
        }
    }
    __syncthreads();
}

__global__ __launch_bounds__(256) void topk_stage1_kernel(
    const u64* __restrict__ keys, u64* __restrict__ cand)
{
    __shared__ u64 s[4096];
    int t = blockIdx.y, ch = blockIdx.x;
    const u64* src = keys + (size_t)t * 65536 + ch * 4096;
    for (int i = threadIdx.x; i < 4096; i += 256) s[i] = src[i];
    bitonic_sort_desc<4096, 256>(s);
    u64* dst = cand + ((size_t)t * 16 + ch) * 512;
    for (int i = threadIdx.x; i < 512; i += 256) dst[i] = s[i];
}

__global__ __launch_bounds__(512) void topk_stage2_kernel(
    const u64* __restrict__ cand, u64* __restrict__ top_keys)
{
    extern __shared__ u64 s2[];
    int t = blockIdx.x;
    for (int i = threadIdx.x; i < 8192; i += 512) s2[i] = cand[(size_t)t * 8192 + i];
    bitonic_sort_desc<8192, 512>(s2);
    for (int i = threadIdx.x; i < 500; i += 512) top_keys[t * 500 + i] = s2[i];
}

// ---------------------------------------------------------------------------
// Final top-300 over 3000 candidates + box decode.
// ---------------------------------------------------------------------------
__global__ __launch_bounds__(256) void final_decode_kernel(
    const u64* __restrict__ top_keys, const float* __restrict__ heads,
    float* __restrict__ qxyz, float* __restrict__ qpred)
{
    __shared__ u64 s[4096];
    int tid = threadIdx.x;
    for (int i = tid; i < 4096; i += 256) {
        u64 v = 0;
        if (i < 3000) {
            u64 k = top_keys[i];
            v = (k & 0xFFFFFFFF00000000ull) | (u64)(u32)(~(u32)i);
        }
        s[i] = v;
    }
    bitonic_sort_desc<4096, 256>(s);
    for (int q = tid; q < 300; q += 256) {
        u64 k2 = s[q];
        u32 gpos = ~(u32)(k2 & 0xFFFFFFFFull);
        int t = gpos / 500;
        u64 ok = top_keys[gpos];
        float score = __uint_as_float((u32)(ok >> 32));
        u32 comb = ~(u32)(ok & 0xFFFFFFFFull);
        int p = (int)(comb % HW);
        int yy = p / IMG, xx = p - yy * IMG;
        const float* hd = heads + (size_t)t * 10 * HW;
        float reg0 = hd[0 * HW + p], reg1 = hd[1 * HW + p], hei = hd[2 * HW + p];
        float d0 = expf(hd[3 * HW + p]);
        float d1 = expf(hd[4 * HW + p]);
        float d2 = expf(hd[5 * HW + p]);
        float rot0 = hd[6 * HW + p], rot1 = hd[7 * HW + p];
        float vel0 = hd[8 * HW + p], vel1 = hd[9 * HW + p];
        float yaw = atan2f(rot0, rot1);
        float X = ((float)xx + reg0) * 8.0f * 0.075f + (-54.0f);
        float Y = ((float)yy + reg1) * 8.0f * 0.075f + (-54.0f);
        qxyz[q * 3 + 0] = X;
        qxyz[q * 3 + 1] = Y;
        qxyz[q * 3 + 2] = hei;
        qpred[q * 7 + 0] = d0; qpred[q * 7 + 1] = d1; qpred[q * 7 + 2] = d2;
        qpred[q * 7 + 3] = yaw; qpred[q * 7 + 4] = vel0; qpred[q * 7 + 5] = vel1;
        qpred[q * 7 + 6] = score;
    }
}

// ---------------------------------------------------------------------------
// Bilinear grid sample of neck at 300 queries + positional embedding.
// ---------------------------------------------------------------------------
__global__ __launch_bounds__(256) void sample_embed_kernel(
    const float* __restrict__ neck, const float* __restrict__ qxyz,
    const float* __restrict__ qpred, float* __restrict__ qf,
    float* __restrict__ emb)
{
    int q = blockIdx.x;
    int tid = threadIdx.x;
    float X = qxyz[q * 3 + 0], Y = qxyz[q * 3 + 1];
    float xn = (X - (-54.0f)) / 108.0f * 2.0f - 1.0f;
    float yn = (Y - (-54.0f)) / 108.0f * 2.0f - 1.0f;
    float gx = (xn + 1.0f) * 180.0f / 2.0f - 0.5f;
    float gy = (yn + 1.0f) * 180.0f / 2.0f - 0.5f;
    float x0f = floorf(gx), y0f = floorf(gy);
    float wx = gx - x0f, wy = gy - y0f;
    int x0 = (int)x0f, y0 = (int)y0f;
    int xs[4] = {x0, x0 + 1, x0, x0 + 1};
    int ys[4] = {y0, y0, y0 + 1, y0 + 1};
    float wt[4] = {(1.f - wx) * (1.f - wy), wx * (1.f - wy),
                   (1.f - wx) * wy, wx * wy};
    int idx[4]; float wv[4];
#pragma unroll
    for (int k = 0; k < 4; ++k) {
        bool valid = xs[k] >= 0 && xs[k] < IMG && ys[k] >= 0 && ys[k] < IMG;
        int cx = xs[k] < 0 ? 0 : (xs[k] > IMG - 1 ? IMG - 1 : xs[k]);
        int cy = ys[k] < 0 ? 0 : (ys[k] > IMG - 1 ? IMG - 1 : ys[k]);
        idx[k] = cy * IMG + cx;
        wv[k] = valid ? wt[k] : 0.f;
    }
    for (int c = tid; c < 512; c += 256) {
        const float* f = neck + (size_t)c * HW;
        float v = f[idx[0]] * wv[0] + f[idx[1]] * wv[1] +
                  f[idx[2]] * wv[2] + f[idx[3]] * wv[3];
        qf[q * 512 + c] = v;
    }
    if (tid < 224) {
        int fidx = tid >> 5; int j = tid & 31; int m = j >> 1;
        float pos = qpred[q * 7 + fidx] * 6.283185307179586f;
        float dt = 2.0f * (float)m / 32.0f + 1.0f;
        float v = pos / dt;
        emb[q * 224 + tid] = (j & 1) ? cosf(v) : sinf(v);
    }
}

// ---------------------------------------------------------------------------
// qf_out = qf @ w_qe^T + b_qe + qf + emb @ w_qpe^T + b_qpe
// ---------------------------------------------------------------------------
__global__ __launch_bounds__(256) void qfout_kernel(
    const float* __restrict__ qf, const float* __restrict__ emb,
    const float* __restrict__ w_qe, const float* __restrict__ b_qe,
    const float* __restrict__ w_qpe, const float* __restrict__ b_qpe,
    float* __restrict__ outq)
{
    int g = blockIdx.x * 256 + threadIdx.x;
    if (g >= 300 * 512) return;
    int q = g >> 9, o = g & 511;
    const float* qrow = qf + q * 512;
    const float* wrow = w_qe + (size_t)o * 512;
    float acc = 0.f;
    for (int c = 0; c < 512; ++c) acc = fmaf(qrow[c], wrow[c], acc);
    const float* erow = emb + q * 224;
    const float* wr2 = w_qpe + (size_t)o * 224;
    float acc2 = 0.f;
    for (int j = 0; j < 224; ++j) acc2 = fmaf(erow[j], wr2[j], acc2);
    outq[g] = acc + b_qe[o] + qrow[o] + acc2 + b_qpe[o];
}

// ---------------------------------------------------------------------------
// bev_out[p][o] = sum_c neck[c][p] * w_pre[o][c] + b_pre[o] + neck[o][p]
// ---------------------------------------------------------------------------
__global__ __launch_bounds__(256) void bev_out_kernel(
    const float* __restrict__ neck, const float* __restrict__ w_pre,
    const float* __restrict__ b_pre, float* __restrict__ outb)
{
    __shared__ float sA[16][132];
    __shared__ float sB[16][132];
    int per = gridDim.x >> 3;
    int g = (blockIdx.x & 7) * per + (blockIdx.x >> 3);
    int pt = g >> 2; int ob = g & 3;
    int p0 = pt * 128, o0 = ob * 128;
    int tid = threadIdx.x, tx = tid & 15, ty = tid >> 4;
    float acc[8][8];
#pragma unroll
    for (int i = 0; i < 8; ++i)
#pragma unroll
        for (int j = 0; j < 8; ++j) acc[i][j] = 0.f;

    for (int c0 = 0; c0 < 512; c0 += 16) {
        for (int e = tid; e < 2048; e += 256) {
            int k = e >> 7, p = e & 127;
            int gp = p0 + p;
            sA[k][p] = gp < HW ? neck[(size_t)(c0 + k) * HW + gp] : 0.f;
        }
        for (int e4 = tid; e4 < 512; e4 += 256) {
            int o = e4 >> 2, kk = e4 & 3;
            float4 v = *(const float4*)&w_pre[(size_t)(o0 + o) * 512 + c0 + kk * 4];
            sB[kk * 4 + 0][o] = v.x; sB[kk * 4 + 1][o] = v.y;
            sB[kk * 4 + 2][o] = v.z; sB[kk * 4 + 3][o] = v.w;
        }
        __syncthreads();
#pragma unroll
        for (int k = 0; k < 16; ++k) {
            float4 a0 = *(const float4*)&sA[k][ty * 4];
            float4 a1 = *(const float4*)&sA[k][64 + ty * 4];
            float4 b0 = *(const float4*)&sB[k][tx * 4];
            float4 b1 = *(const float4*)&sB[k][64 + tx * 4];
            float av[8] = {a0.x, a0.y, a0.z, a0.w, a1.x, a1.y, a1.z, a1.w};
            float bv[8] = {b0.x, b0.y, b0.z, b0.w, b1.x, b1.y, b1.z, b1.w};
#pragma unroll
            for (int i = 0; i < 8; ++i)
#pragma unroll
                for (int j = 0; j < 8; ++j)
                    acc[i][j] = fmaf(av[i], bv[j], acc[i][j]);
        }
        __syncthreads();
    }
#pragma unroll
    for (int i = 0; i < 8; ++i) {
        int pl = (i < 4) ? (ty * 4 + i) : (64 + ty * 4 + i - 4);
        int p = p0 + pl;
        if (p >= HW) continue;
#pragma unroll
        for (int j = 0; j < 8; ++j) {
            int ol = (j < 4) ? (tx * 4 + j) : (64 + tx * 4 + j - 4);
            int o = o0 + ol;
            outb[(size_t)p * 512 + o] =
                acc[i][j] + b_pre[o] + neck[(size_t)o * HW + p];
        }
    }
}

// ---------------------------------------------------------------------------
extern "C" void kernel_launch(void* const* d_in, const int* in_sizes, int n_in,
                              void* d_out, int out_size, void* d_ws, size_t ws_size,
                              hipStream_t stream)
{
    (void)in_sizes; (void)n_in; (void)out_size; (void)ws_size;

    const float* bev   = (const float*)d_in[0];
    const float* w_b0  = (const float*)d_in[1];
    const float* b_b0  = (const float*)d_in[2];
    const float* w_b1  = (const float*)d_in[3];
    const float* b_b1  = (const float*)d_in[4];
    const float* w_n0  = (const float*)d_in[5];
    const float* b_n0  = (const float*)d_in[6];
    const float* w_n1  = (const float*)d_in[7];
    const float* b_n1  = (const float*)d_in[8];
    const float* w_sh  = (const float*)d_in[9];
    const float* b_sh  = (const float*)d_in[10];
    const float* w_hm  = (const float*)d_in[11];
    const float* b_hm  = (const float*)d_in[12];
    const float* w_reg = (const float*)d_in[13];
    const float* b_reg = (const float*)d_in[14];
    const float* w_hei = (const float*)d_in[15];
    const float* b_hei = (const float*)d_in[16];
    const float* w_dim = (const float*)d_in[17];
    const float* b_dim = (const float*)d_in[18];
    const float* w_rot = (const float*)d_in[19];
    const float* b_rot = (const float*)d_in[20];
    const float* w_vel = (const float*)d_in[21];
    const float* b_vel = (const float*)d_in[22];
    const float* w_pre = (const float*)d_in[23];
    const float* b_pre = (const float*)d_in[24];
    const float* w_qe  = (const float*)d_in[25];
    const float* b_qe  = (const float*)d_in[26];
    const float* w_qpe = (const float*)d_in[27];
    const float* b_qpe = (const float*)d_in[28];

    float* out = (float*)d_out;
    float* wsf = (float*)d_ws;

    float* x0    = wsf;
    float* x1    = x0 + (size_t)128 * HW;
    float* neck  = x1 + (size_t)256 * 8100;
    float* sh    = neck + (size_t)512 * HW;
    float* heads = sh + (size_t)NTASK * 64 * HW;
    float* hm    = heads + (size_t)NTASK * 10 * HW;
    float* qpred = hm + (size_t)NTASK * 2 * HW;
    float* qf    = qpred + 300 * 7;
    float* emb   = qf + 300 * 512;
    u64* keys    = (u64*)(emb + 300 * 224);
    u64* cand    = keys + (size_t)NTASK * 65536;
    u64* topk    = cand + (size_t)NTASK * 16 * 512;
    float* zp    = (float*)(((uintptr_t)(topk + 3008) + 63) & ~(uintptr_t)63);

    float* out_bev = out;
    float* out_qf  = out + (size_t)HW * 512;
    float* out_xyz = out + (size_t)HW * 512 + 300 * 512;

    zp_init_kernel<<<dim3(1), dim3(64), 0, stream>>>(zp);

    // block0: 256->128, n_ocb = 8 (16 oc each), grid 288 (div by 8)
    conv3x3_relu_v19<<<dim3(288), dim3(512), 0, stream>>>(
        bev, w_b0, b_b0, x0, zp, 256, 8);
    conv3x3s2_relu_v2<<<dim3(36, 16), dim3(256), 0, stream>>>(
        x0, w_b1, b_b1, x1);
    conv1x1_relu_kernel<<<dim3(127, 16), dim3(256), 0, stream>>>(
        x0, w_n0, b_n0, neck);
    deconv2x2_relu_kernel<<<dim3(32, 16), dim3(256), 0, stream>>>(
        x1, w_n1, b_n1, neck + (size_t)256 * HW);
    // shared heads: 512->384 (6 tasks x 64 oc folded), n_ocb = 24, grid 864
    conv3x3_relu_v19<<<dim3(864), dim3(512), 0, stream>>>(
        neck, w_sh, b_sh, sh, zp, 512, 24);
    heads_kernel<<<dim3(127, 6), dim3(256), 0, stream>>>(
        sh, w_hm, b_hm, w_reg, b_reg, w_hei, b_hei, w_dim, b_dim,
        w_rot, b_rot, w_vel, b_vel, hm, heads);
    nms_key_kernel<<<dim3(256, 6), dim3(256), 0, stream>>>(hm, keys);
    topk_stage1_kernel<<<dim3(16, 6), dim3(256), 0, stream>>>(keys, cand);
    topk_stage2_kernel<<<dim3(6), dim3(512), 65536, stream>>>(cand, topk);
    final_decode_kernel<<<dim3(1), dim3(256), 0, stream>>>(
        topk, heads, out_xyz, qpred);
    sample_embed_kernel<<<dim3(300), dim3(256), 0, stream>>>(
        neck, out_xyz, qpred, qf, emb);
    qfout_kernel<<<dim3(600), dim3(256), 0, stream>>>(
        qf, emb, w_qe, b_qe, w_qpe, b_qpe, out_qf);
    bev_out_kernel<<<dim3(1016), dim3(256), 0, stream>>>(
        neck, w_pre, b_pre, out_bev);
}

// Round 20
// 3642.904 us; speedup vs baseline: 1.0558x; 1.0558x over previous
//
#include <hip/hip_runtime.h>

typedef unsigned long long u64;
typedef unsigned int u32;

#define HW 32400
#define IMG 180
#define NTASK 6

__constant__ int c_nc[NTASK] = {1, 2, 2, 1, 2, 2};

// async global->LDS, 16B per lane, wave-uniform LDS base
#define GLL16(SRC, DST)                                                      \
    __builtin_amdgcn_global_load_lds(                                        \
        (const __attribute__((address_space(1))) unsigned int*)(SRC),        \
        (__attribute__((address_space(3))) unsigned int*)(DST), 16, 0, 0)

// ---------------------------------------------------------------------------
// zero page init (64 floats) — OOB staging lanes read from here
// ---------------------------------------------------------------------------
__global__ void zp_init_kernel(float* zp)
{
    zp[threadIdx.x] = 0.f;
}

// ---------------------------------------------------------------------------
// 3x3 stride-1 pad-1 conv + ReLU, v18 (PROVEN BEST: conflicts 0, 1766us,
// 40 VGPR). Strided pixel ownership x = xg+{0,8,16,24} (xg=tid&7) kills the
// 8-way input-read bank conflicts: read addr = 40y + xg + C -> bank
// (8y+xg+C)%32 -> 32 banks x 2 lanes (free, m136). GLL16 async staging
// ([3 ic][34][40] row-major, +4-col shift, zero page OOB), weights via LDS
// broadcast, 3-ic chunks double-buffered, one barrier/chunk, 512 thr,
// 16 oc (two 8-oc halves). grid.x = 36*n_ocb, XCD-swizzled.
// ---------------------------------------------------------------------------
__device__ __forceinline__ void stage_in_async3(
    const float* __restrict__ in, const float* __restrict__ zp,
    float* lds_buf, int ic0, int IC, int ty0, int tx0, int tid)
{
    int lane = tid & 63;
    int wv = tid >> 6;          // 0..7
#pragma unroll
    for (int kk = 0; kk < 2; ++kk) {
        int k = wv + kk * 8;    // 0..15; 3*1360 = 4080 words = 16 issues
        int e = k * 256 + lane * 4;       // word index, mult of 4
        if (e < 4080) {
            int ic = e / 1360;            // 0..2
            int r2 = e - ic * 1360;
            int rr = r2 / 40;
            int cc = r2 - rr * 40;        // mult of 4
            int gy = ty0 - 1 + rr;
            int gx0 = tx0 - 4 + cc;       // 16B-aligned source col
            const float* src = zp;
            if (ic0 + ic < IC && (unsigned)gy < 180u && (unsigned)gx0 < 180u)
                src = in + (size_t)(ic0 + ic) * HW + (size_t)(gy * IMG + gx0);
            GLL16(src, lds_buf + e);
        }
    }
}

__global__ __launch_bounds__(512) void conv3x3_relu_v18(
    const float* __restrict__ in, const float* __restrict__ wgt,
    const float* __restrict__ bias, float* __restrict__ out,
    const float* __restrict__ zp, int IC, int n_ocb)
{
    __shared__ float s_in[2][4080];   // 3 ic x 34 rows x 40 cols
    __shared__ float s_w[2][432];     // [ic][tap][oc] flat (3*9*16)

    int per = gridDim.x >> 3;
    int g = (blockIdx.x & 7) * per + (blockIdx.x >> 3);
    int sp = g / n_ocb;
    int ocb = g - sp * n_ocb;
    int oc0 = ocb * 16;
    int ty0 = (sp / 6) * 32, tx0 = (sp % 6) * 32;

    int tid = threadIdx.x;
    int sub = tid >> 8;          // oc half
    int t8 = tid & 255;
    int xg = t8 & 7, y = t8 >> 3;
    int sub8 = sub * 8;

    const int NC = (IC + 2) / 3;   // last chunk padded

    // weight-load thread mapping (tid < 432): wq = tid>>4 in 0..26
    int wq = tid >> 4;
    int w_ic = wq / 9, w_tap = wq - w_ic * 9, w_oc = tid & 15;
    bool w_on = tid < 432;

    float acc[4][8];
#pragma unroll
    for (int p = 0; p < 4; ++p)
#pragma unroll
        for (int o = 0; o < 8; ++o) acc[p][o] = 0.f;

    // ---- prologue: stage chunk 0 into buffer 0 ----
    {
        float wA = 0.f;
        if (w_on && w_ic < IC)
            wA = wgt[((size_t)(oc0 + w_oc) * IC + w_ic) * 9 + w_tap];
        stage_in_async3(in, zp, &s_in[0][0], 0, IC, ty0, tx0, tid);
        if (w_on) s_w[0][tid] = wA;
    }
    __syncthreads();

    for (int c = 0; c < NC; ++c) {
        int cur = c & 1;

        // ---- prefetch chunk c+1 (weights->regs, async inputs,
        //      weights->LDS) ----
        if (c + 1 < NC) {
            int nic0 = (c + 1) * 3;
            float wN = 0.f;
            if (w_on && nic0 + w_ic < IC)
                wN = wgt[((size_t)(oc0 + w_oc) * IC + nic0 + w_ic) * 9 + w_tap];
            stage_in_async3(in, zp, &s_in[cur ^ 1][0], nic0, IC, ty0, tx0, tid);
            if (w_on) s_w[cur ^ 1][tid] = wN;
        }

        // ---- compute chunk c (3 ic); strided pixels xg+{0,8,16,24} ----
        {
            const float* sbuf = &s_in[cur][0];
            const float* swb = &s_w[cur][0];
#pragma unroll
            for (int ic = 0; ic < 3; ++ic) {
#pragma unroll
                for (int dy = 0; dy < 3; ++dy) {
                    // base col for p=0,dx=0: gx = tx0+xg-1 -> LDS col xg+3
                    const float* rowb =
                        sbuf + ic * 1360 + (y + dy) * 40 + xg + 3;
#pragma unroll
                    for (int p = 0; p < 4; ++p) {
                        float v0 = rowb[8 * p + 0];
                        float v1 = rowb[8 * p + 1];
                        float v2 = rowb[8 * p + 2];
                        float vv[3] = {v0, v1, v2};
#pragma unroll
                        for (int dx = 0; dx < 3; ++dx) {
                            const float* wpp =
                                swb + (ic * 9 + dy * 3 + dx) * 16 + sub8;
                            float4 w0 = *(const float4*)(wpp + 0);
                            float4 w1 = *(const float4*)(wpp + 4);
                            float wvv[8] = {w0.x, w0.y, w0.z, w0.w,
                                            w1.x, w1.y, w1.z, w1.w};
                            float* ar = acc[p];
#pragma unroll
                            for (int o = 0; o < 8; ++o)
                                ar[o] = fmaf(vv[dx], wvv[o], ar[o]);
                        }
                    }
                }
            }
        }
        __syncthreads();   // drains async loads (issued ~full compute ago)
    }

    // ---- epilogue: bias + relu + strided scalar stores ----
    int gy = ty0 + y;
    if (gy < IMG) {
#pragma unroll
        for (int p = 0; p < 4; ++p) {
            int gxp = tx0 + xg + 8 * p;
            if (gxp < IMG) {
#pragma unroll
                for (int o = 0; o < 8; ++o) {
                    float r = acc[p][o] + bias[oc0 + sub8 + o];
                    r = r > 0.f ? r : 0.f;
                    out[(size_t)(oc0 + sub8 + o) * HW + gy * IMG + gxp] = r;
                }
            }
        }
    }
}

// ---------------------------------------------------------------------------
// 3x3 stride-2 pad-1 conv + ReLU, v3: 4-ic chunks (half the barriers of v2).
// ---------------------------------------------------------------------------
__global__ __launch_bounds__(256) void conv3x3s2_relu_v3(
    const float* __restrict__ in, const float* __restrict__ wgt,
    const float* __restrict__ bias, float* __restrict__ out)
{
    __shared__ float s_in[4][31][34];
    __shared__ float s_w[4][9][16];

    int sp = blockIdx.x; int ocb = blockIdx.y;
    int oty0 = (sp / 6) * 15, otx0 = (sp % 6) * 15;
    int iy0 = 2 * oty0 - 1, ix0 = 2 * otx0 - 1;
    int tid = threadIdx.x;
    int tx = tid & 15, ty = tid >> 4;
    bool active = (tx < 15) && (ty < 15);

    float acc[16];
#pragma unroll
    for (int o = 0; o < 16; ++o) acc[o] = 0.f;

    for (int ic0 = 0; ic0 < 128; ic0 += 4) {
        __syncthreads();
        for (int e = tid; e < 4 * 31 * 31; e += 256) {
            int ic = e / 961; int rem = e - ic * 961;
            int rr = rem / 31; int cc = rem - rr * 31;
            int gy = iy0 + rr, gx = ix0 + cc;
            float v = 0.f;
            if ((unsigned)gy < 180u && (unsigned)gx < 180u)
                v = in[(size_t)(ic0 + ic) * HW + gy * IMG + gx];
            s_in[ic][rr][cc] = v;
        }
        for (int e = tid; e < 576; e += 256) {
            int oc = e & 15; int tap = (e >> 4) % 9; int ic = e / 144;
            s_w[ic][tap][oc] =
                wgt[((size_t)(ocb * 16 + oc) * 128 + ic0 + ic) * 9 + tap];
        }
        __syncthreads();
        if (!active) continue;
#pragma unroll
        for (int ic = 0; ic < 4; ++ic) {
#pragma unroll
            for (int tap = 0; tap < 9; ++tap) {
                int dy = tap / 3, dx = tap - dy * 3;
                float v = s_in[ic][2 * ty + dy][2 * tx + dx];
                float4 w0 = *(const float4*)&s_w[ic][tap][0];
                float4 w1 = *(const float4*)&s_w[ic][tap][4];
                float4 w2 = *(const float4*)&s_w[ic][tap][8];
                float4 w3 = *(const float4*)&s_w[ic][tap][12];
                float wv[16] = {w0.x, w0.y, w0.z, w0.w, w1.x, w1.y, w1.z, w1.w,
                                w2.x, w2.y, w2.z, w2.w, w3.x, w3.y, w3.z, w3.w};
#pragma unroll
                for (int o = 0; o < 16; ++o) acc[o] = fmaf(v, wv[o], acc[o]);
            }
        }
    }
    if (active) {
        int yy = oty0 + ty, xx = otx0 + tx;
#pragma unroll
        for (int o = 0; o < 16; ++o) {
            float r = acc[o] + bias[ocb * 16 + o];
            out[(size_t)(ocb * 16 + o) * 8100 + yy * 90 + xx] =
                r > 0.f ? r : 0.f;
        }
    }
}

// ---------------------------------------------------------------------------
// 1x1 conv 128->256 + ReLU, v2: 16-ic chunks (half the barriers).
// ---------------------------------------------------------------------------
__global__ __launch_bounds__(256) void conv1x1_relu_kernel(
    const float* __restrict__ in, const float* __restrict__ w,
    const float* __restrict__ bias, float* __restrict__ out)
{
    __shared__ float s_x[16][256];
    __shared__ float s_w[16][16];
    int p0 = blockIdx.x * 256; int ocb = blockIdx.y;
    int tid = threadIdx.x;
    float acc[16];
#pragma unroll
    for (int o = 0; o < 16; ++o) acc[o] = 0.f;

    for (int ic0 = 0; ic0 < 128; ic0 += 16) {
        __syncthreads();
        for (int e = tid; e < 4096; e += 256) {
            int ic = e >> 8; int p = e & 255;
            s_x[ic][p] = (p0 + p < HW) ? in[(size_t)(ic0 + ic) * HW + p0 + p] : 0.f;
        }
        for (int e = tid; e < 256; e += 256) {
            int ic = e >> 4; int oc = e & 15;
            s_w[ic][oc] = w[(size_t)(ocb * 16 + oc) * 128 + ic0 + ic];
        }
        __syncthreads();
#pragma unroll
        for (int ic = 0; ic < 16; ++ic) {
            float v = s_x[ic][tid];
            float4 w0 = *(const float4*)&s_w[ic][0];
            float4 w1 = *(const float4*)&s_w[ic][4];
            float4 w2 = *(const float4*)&s_w[ic][8];
            float4 w3 = *(const float4*)&s_w[ic][12];
            float wv[16] = {w0.x, w0.y, w0.z, w0.w, w1.x, w1.y, w1.z, w1.w,
                            w2.x, w2.y, w2.z, w2.w, w3.x, w3.y, w3.z, w3.w};
#pragma unroll
            for (int o = 0; o < 16; ++o) acc[o] = fmaf(v, wv[o], acc[o]);
        }
    }
    int p = p0 + tid;
    if (p < HW) {
#pragma unroll
        for (int o = 0; o < 16; ++o) {
            float r = acc[o] + bias[ocb * 16 + o];
            out[(size_t)(ocb * 16 + o) * HW + p] = r > 0.f ? r : 0.f;
        }
    }
}

// ---------------------------------------------------------------------------
// 2x2 stride-2 transposed conv + ReLU, v2: 16-ic chunks (half the barriers).
// x1[256][90][90] -> neck ch 256..511
// ---------------------------------------------------------------------------
__global__ __launch_bounds__(256) void deconv2x2_relu_kernel(
    const float* __restrict__ in, const float* __restrict__ wgt,
    const float* __restrict__ bias, float* __restrict__ out)
{
    __shared__ float s_x[16][256];
    __shared__ float s_w[16][4][16];
    int p0 = blockIdx.x * 256; int ocb = blockIdx.y;
    int tid = threadIdx.x;
    float acc[4][16];
#pragma unroll
    for (int ab = 0; ab < 4; ++ab)
#pragma unroll
        for (int o = 0; o < 16; ++o) acc[ab][o] = 0.f;

    for (int ic0 = 0; ic0 < 256; ic0 += 16) {
        __syncthreads();
        for (int e = tid; e < 4096; e += 256) {
            int ic = e >> 8; int p = e & 255;
            s_x[ic][p] = (p0 + p < 8100) ? in[(size_t)(ic0 + ic) * 8100 + p0 + p] : 0.f;
        }
        for (int e = tid; e < 1024; e += 256) {
            int oc = e & 15; int ab = (e >> 4) & 3; int ic = e >> 6;
            s_w[ic][ab][oc] =
                wgt[((size_t)(ocb * 16 + oc) * 256 + ic0 + ic) * 4 + ab];
        }
        __syncthreads();
#pragma unroll
        for (int ic = 0; ic < 16; ++ic) {
            float v = s_x[ic][tid];
#pragma unroll
            for (int ab = 0; ab < 4; ++ab) {
                float4 w0 = *(const float4*)&s_w[ic][ab][0];
                float4 w1 = *(const float4*)&s_w[ic][ab][4];
                float4 w2 = *(const float4*)&s_w[ic][ab][8];
                float4 w3 = *(const float4*)&s_w[ic][ab][12];
                float wv[16] = {w0.x, w0.y, w0.z, w0.w, w1.x, w1.y, w1.z, w1.w,
                                w2.x, w2.y, w2.z, w2.w, w3.x, w3.y, w3.z, w3.w};
#pragma unroll
                for (int o = 0; o < 16; ++o)
                    acc[ab][o] = fmaf(v, wv[o], acc[ab][o]);
            }
        }
    }
    int sp = p0 + tid;
    if (sp < 8100) {
        int sy = sp / 90, sx = sp - sy * 90;
#pragma unroll
        for (int ab = 0; ab < 4; ++ab) {
            int a = ab >> 1, bb = ab & 1;
            int Y = 2 * sy + a, X = 2 * sx + bb;
#pragma unroll
            for (int o = 0; o < 16; ++o) {
                float r = acc[ab][o] + bias[ocb * 16 + o];
                out[(size_t)(ocb * 16 + o) * HW + Y * IMG + X] = r > 0.f ? r : 0.f;
            }
        }
    }
}

// ---------------------------------------------------------------------------
// Per-pixel 1x1 heads (12 outputs from 64 ch) + sigmoid on hm channels.
// ---------------------------------------------------------------------------
__global__ __launch_bounds__(256) void heads_kernel(
    const float* __restrict__ sh,
    const float* __restrict__ w_hm, const float* __restrict__ b_hm,
    const float* __restrict__ w_reg, const float* __restrict__ b_reg,
    const float* __restrict__ w_hei, const float* __restrict__ b_hei,
    const float* __restrict__ w_dim, const float* __restrict__ b_dim,
    const float* __restrict__ w_rot, const float* __restrict__ b_rot,
    const float* __restrict__ w_vel, const float* __restrict__ b_vel,
    float* __restrict__ hm_sig, float* __restrict__ heads)
{
    __shared__ float s_w[64][12];
    __shared__ float s_b[12];
    int t = blockIdx.y;
    int tid = threadIdx.x;
    for (int e = tid; e < 768; e += 256) {
        int c = e / 12; int r = e - c * 12;
        float v;
        if (r < 2)       v = w_hm [(t * 2 + r) * 64 + c];
        else if (r < 4)  v = w_reg[(t * 2 + r - 2) * 64 + c];
        else if (r < 5)  v = w_hei[t * 64 + c];
        else if (r < 8)  v = w_dim[(t * 3 + r - 5) * 64 + c];
        else if (r < 10) v = w_rot[(t * 2 + r - 8) * 64 + c];
        else             v = w_vel[(t * 2 + r - 10) * 64 + c];
        s_w[c][r] = v;
    }
    if (tid < 12) {
        int r = tid; float v;
        if (r < 2)       v = b_hm [t * 2 + r];
        else if (r < 4)  v = b_reg[t * 2 + r - 2];
        else if (r < 5)  v = b_hei[t];
        else if (r < 8)  v = b_dim[t * 3 + r - 5];
        else if (r < 10) v = b_rot[t * 2 + r - 8];
        else             v = b_vel[t * 2 + r - 10];
        s_b[r] = v;
    }
    __syncthreads();
    int p = blockIdx.x * 256 + tid;
    if (p >= HW) return;
    float a[12];
#pragma unroll
    for (int r = 0; r < 12; ++r) a[r] = 0.f;
    const float* shp = sh + (size_t)t * 64 * HW + p;
    for (int c = 0; c < 64; ++c) {
        float x = shp[(size_t)c * HW];
        float4 w0 = *(const float4*)&s_w[c][0];
        float4 w1 = *(const float4*)&s_w[c][4];
        float4 w2 = *(const float4*)&s_w[c][8];
        float wv[12] = {w0.x, w0.y, w0.z, w0.w, w1.x, w1.y, w1.z, w1.w,
                        w2.x, w2.y, w2.z, w2.w};
#pragma unroll
        for (int r = 0; r < 12; ++r) a[r] = fmaf(x, wv[r], a[r]);
    }
#pragma unroll
    for (int r = 0; r < 12; ++r) a[r] += s_b[r];
    hm_sig[(size_t)(t * 2 + 0) * HW + p] = 1.f / (1.f + expf(-a[0]));
    hm_sig[(size_t)(t * 2 + 1) * HW + p] = 1.f / (1.f + expf(-a[1]));
#pragma unroll
    for (int r = 0; r < 10; ++r)
        heads[(size_t)(t * 10 + r) * HW + p] = a[2 + r];
}

// ---------------------------------------------------------------------------
// 3x3 max-pool NMS -> packed sort keys (score_bits<<32 | ~combined_idx)
// ---------------------------------------------------------------------------
__global__ __launch_bounds__(256) void nms_key_kernel(
    const float* __restrict__ hm_sig, u64* __restrict__ keys)
{
    int t = blockIdx.y;
    int i = blockIdx.x * 256 + threadIdx.x;   // < 65536
    int nc = c_nc[t];
    u64 key = 0;
    if (i < nc * HW) {
        int c = i / HW; int p = i - c * HW;
        int y = p / IMG; int x = p - y * IMG;
        const float* base = hm_sig + (size_t)(t * 2 + c) * HW;
        float s = base[p];
        float m = s;
#pragma unroll
        for (int dy = -1; dy <= 1; ++dy)
#pragma unroll
            for (int dx = -1; dx <= 1; ++dx) {
                int yy = y + dy, xx = x + dx;
                if ((unsigned)yy < 180u && (unsigned)xx < 180u)
                    m = fmaxf(m, base[yy * IMG + xx]);
            }
        float sm = (s == m) ? s : 0.f;
        key = ((u64)__float_as_uint(sm) << 32) | (u64)(u32)(~(u32)i);
    }
    keys[(size_t)t * 65536 + i] = key;
}

// ---------------------------------------------------------------------------
// Bitonic sort (descending) of N u64 keys in LDS, T threads.
// ---------------------------------------------------------------------------
template <int N, int T>
__device__ void bitonic_sort_desc(u64* s)
{
    const int tid = threadIdx.x;
    for (int k = 2; k <= N; k <<= 1) {
        for (int j = k >> 1; j > 0; j >>= 1) {
            __syncthreads();
            for (int idx = tid; idx < N / 2; idx += T) {
                int i = ((idx & ~(j - 1)) << 1) | (idx & (j - 1));
                int l = i | j;
                u64 a = s[i], b = s[l];
                bool sw = ((i & k) == 0) ? (a < b) : (a > b);
                if (sw) { s[i] = b; s[l] = a; }
            }
        }
    }
    __syncthreads();
}

__global__ __launch_bounds__(256) void topk_stage1_kernel(
    const u64* __restrict__ keys, u64* __restrict__ cand)
{
    __shared__ u64 s[4096];
    int t = blockIdx.y, ch = blockIdx.x;
    const u64* src = keys + (size_t)t * 65536 + ch * 4096;
    for (int i = threadIdx.x; i < 4096; i += 256) s[i] = src[i];
    bitonic_sort_desc<4096, 256>(s);
    u64* dst = cand + ((size_t)t * 16 + ch) * 512;
    for (int i = threadIdx.x; i < 512; i += 256) dst[i] = s[i];
}

__global__ __launch_bounds__(512) void topk_stage2_kernel(
    const u64* __restrict__ cand, u64* __restrict__ top_keys)
{
    extern __shared__ u64 s2[];
    int t = blockIdx.x;
    for (int i = threadIdx.x; i < 8192; i += 512) s2[i] = cand[(size_t)t * 8192 + i];
    bitonic_sort_desc<8192, 512>(s2);
    for (int i = threadIdx.x; i < 500; i += 512) top_keys[t * 500 + i] = s2[i];
}

// ---------------------------------------------------------------------------
// Final top-300 over 3000 candidates + box decode.
// ---------------------------------------------------------------------------
__global__ __launch_bounds__(256) void final_decode_kernel(
    const u64* __restrict__ top_keys, const float* __restrict__ heads,
    float* __restrict__ qxyz, float* __restrict__ qpred)
{
    __shared__ u64 s[4096];
    int tid = threadIdx.x;
    for (int i = tid; i < 4096; i += 256) {
        u64 v = 0;
        if (i < 3000) {
            u64 k = top_keys[i];
            v = (k & 0xFFFFFFFF00000000ull) | (u64)(u32)(~(u32)i);
        }
        s[i] = v;
    }
    bitonic_sort_desc<4096, 256>(s);
    for (int q = tid; q < 300; q += 256) {
        u64 k2 = s[q];
        u32 gpos = ~(u32)(k2 & 0xFFFFFFFFull);
        int t = gpos / 500;
        u64 ok = top_keys[gpos];
        float score = __uint_as_float((u32)(ok >> 32));
        u32 comb = ~(u32)(ok & 0xFFFFFFFFull);
        int p = (int)(comb % HW);
        int yy = p / IMG, xx = p - yy * IMG;
        const float* hd = heads + (size_t)t * 10 * HW;
        float reg0 = hd[0 * HW + p], reg1 = hd[1 * HW + p], hei = hd[2 * HW + p];
        float d0 = expf(hd[3 * HW + p]);
        float d1 = expf(hd[4 * HW + p]);
        float d2 = expf(hd[5 * HW + p]);
        float rot0 = hd[6 * HW + p], rot1 = hd[7 * HW + p];
        float vel0 = hd[8 * HW + p], vel1 = hd[9 * HW + p];
        float yaw = atan2f(rot0, rot1);
        float X = ((float)xx + reg0) * 8.0f * 0.075f + (-54.0f);
        float Y = ((float)yy + reg1) * 8.0f * 0.075f + (-54.0f);
        qxyz[q * 3 + 0] = X;
        qxyz[q * 3 + 1] = Y;
        qxyz[q * 3 + 2] = hei;
        qpred[q * 7 + 0] = d0; qpred[q * 7 + 1] = d1; qpred[q * 7 + 2] = d2;
        qpred[q * 7 + 3] = yaw; qpred[q * 7 + 4] = vel0; qpred[q * 7 + 5] = vel1;
        qpred[q * 7 + 6] = score;
    }
}

// ---------------------------------------------------------------------------
// Bilinear grid sample of neck at 300 queries + positional embedding.
// ---------------------------------------------------------------------------
__global__ __launch_bounds__(256) void sample_embed_kernel(
    const float* __restrict__ neck, const float* __restrict__ qxyz,
    const float* __restrict__ qpred, float* __restrict__ qf,
    float* __restrict__ emb)
{
    int q = blockIdx.x;
    int tid = threadIdx.x;
    float X = qxyz[q * 3 + 0], Y = qxyz[q * 3 + 1];
    float xn = (X - (-54.0f)) / 108.0f * 2.0f - 1.0f;
    float yn = (Y - (-54.0f)) / 108.0f * 2.0f - 1.0f;
    float gx = (xn + 1.0f) * 180.0f / 2.0f - 0.5f;
    float gy = (yn + 1.0f) * 180.0f / 2.0f - 0.5f;
    float x0f = floorf(gx), y0f = floorf(gy);
    float wx = gx - x0f, wy = gy - y0f;
    int x0 = (int)x0f, y0 = (int)y0f;
    int xs[4] = {x0, x0 + 1, x0, x0 + 1};
    int ys[4] = {y0, y0, y0 + 1, y0 + 1};
    float wt[4] = {(1.f - wx) * (1.f - wy), wx * (1.f - wy),
                   (1.f - wx) * wy, wx * wy};
    int idx[4]; float wv[4];
#pragma unroll
    for (int k = 0; k < 4; ++k) {
        bool valid = xs[k] >= 0 && xs[k] < IMG && ys[k] >= 0 && ys[k] < IMG;
        int cx = xs[k] < 0 ? 0 : (xs[k] > IMG - 1 ? IMG - 1 : xs[k]);
        int cy = ys[k] < 0 ? 0 : (ys[k] > IMG - 1 ? IMG - 1 : ys[k]);
        idx[k] = cy * IMG + cx;
        wv[k] = valid ? wt[k] : 0.f;
    }
    for (int c = tid; c < 512; c += 256) {
        const float* f = neck + (size_t)c * HW;
        float v = f[idx[0]] * wv[0] + f[idx[1]] * wv[1] +
                  f[idx[2]] * wv[2] + f[idx[3]] * wv[3];
        qf[q * 512 + c] = v;
    }
    if (tid < 224) {
        int fidx = tid >> 5; int j = tid & 31; int m = j >> 1;
        float pos = qpred[q * 7 + fidx] * 6.283185307179586f;
        float dt = 2.0f * (float)m / 32.0f + 1.0f;
        float v = pos / dt;
        emb[q * 224 + tid] = (j & 1) ? cosf(v) : sinf(v);
    }
}

// ---------------------------------------------------------------------------
// qf_out = qf @ w_qe^T + b_qe + qf + emb @ w_qpe^T + b_qpe
// ---------------------------------------------------------------------------
__global__ __launch_bounds__(256) void qfout_kernel(
    const float* __restrict__ qf, const float* __restrict__ emb,
    const float* __restrict__ w_qe, const float* __restrict__ b_qe,
    const float* __restrict__ w_qpe, const float* __restrict__ b_qpe,
    float* __restrict__ outq)
{
    int g = blockIdx.x * 256 + threadIdx.x;
    if (g >= 300 * 512) return;
    int q = g >> 9, o = g & 511;
    const float* qrow = qf + q * 512;
    const float* wrow = w_qe + (size_t)o * 512;
    float acc = 0.f;
    for (int c = 0; c < 512; ++c) acc = fmaf(qrow[c], wrow[c], acc);
    const float* erow = emb + q * 224;
    const float* wr2 = w_qpe + (size_t)o * 224;
    float acc2 = 0.f;
    for (int j = 0; j < 224; ++j) acc2 = fmaf(erow[j], wr2[j], acc2);
    outq[g] = acc + b_qe[o] + qrow[o] + acc2 + b_qpe[o];
}

// ---------------------------------------------------------------------------
// bev_out[p][o] = sum_c neck[c][p] * w_pre[o][c] + b_pre[o] + neck[o][p]
// ---------------------------------------------------------------------------
__global__ __launch_bounds__(256) void bev_out_kernel(
    const float* __restrict__ neck, const float* __restrict__ w_pre,
    const float* __restrict__ b_pre, float* __restrict__ outb)
{
    __shared__ float sA[16][132];
    __shared__ float sB[16][132];
    int per = gridDim.x >> 3;
    int g = (blockIdx.x & 7) * per + (blockIdx.x >> 3);
    int pt = g >> 2; int ob = g & 3;
    int p0 = pt * 128, o0 = ob * 128;
    int tid = threadIdx.x, tx = tid & 15, ty = tid >> 4;
    float acc[8][8];
#pragma unroll
    for (int i = 0; i < 8; ++i)
#pragma unroll
        for (int j = 0; j < 8; ++j) acc[i][j] = 0.f;

    for (int c0 = 0; c0 < 512; c0 += 16) {
        for (int e = tid; e < 2048; e += 256) {
            int k = e >> 7, p = e & 127;
            int gp = p0 + p;
            sA[k][p] = gp < HW ? neck[(size_t)(c0 + k) * HW + gp] : 0.f;
        }
        for (int e4 = tid; e4 < 512; e4 += 256) {
            int o = e4 >> 2, kk = e4 & 3;
            float4 v = *(const float4*)&w_pre[(size_t)(o0 + o) * 512 + c0 + kk * 4];
            sB[kk * 4 + 0][o] = v.x; sB[kk * 4 + 1][o] = v.y;
            sB[kk * 4 + 2][o] = v.z; sB[kk * 4 + 3][o] = v.w;
        }
        __syncthreads();
#pragma unroll
        for (int k = 0; k < 16; ++k) {
            float4 a0 = *(const float4*)&sA[k][ty * 4];
            float4 a1 = *(const float4*)&sA[k][64 + ty * 4];
            float4 b0 = *(const float4*)&sB[k][tx * 4];
            float4 b1 = *(const float4*)&sB[k][64 + tx * 4];
            float av[8] = {a0.x, a0.y, a0.z, a0.w, a1.x, a1.y, a1.z, a1.w};
            float bv[8] = {b0.x, b0.y, b0.z, b0.w, b1.x, b1.y, b1.z, b1.w};
#pragma unroll
            for (int i = 0; i < 8; ++i)
#pragma unroll
                for (int j = 0; j < 8; ++j)
                    acc[i][j] = fmaf(av[i], bv[j], acc[i][j]);
        }
        __syncthreads();
    }
#pragma unroll
    for (int i = 0; i < 8; ++i) {
        int pl = (i < 4) ? (ty * 4 + i) : (64 + ty * 4 + i - 4);
        int p = p0 + pl;
        if (p >= HW) continue;
#pragma unroll
        for (int j = 0; j < 8; ++j) {
            int ol = (j < 4) ? (tx * 4 + j) : (64 + tx * 4 + j - 4);
            int o = o0 + ol;
            outb[(size_t)p * 512 + o] =
                acc[i][j] + b_pre[o] + neck[(size_t)o * HW + p];
        }
    }
}

// ---------------------------------------------------------------------------
extern "C" void kernel_launch(void* const* d_in, const int* in_sizes, int n_in,
                              void* d_out, int out_size, void* d_ws, size_t ws_size,
                              hipStream_t stream)
{
    (void)in_sizes; (void)n_in; (void)out_size; (void)ws_size;

    const float* bev   = (const float*)d_in[0];
    const float* w_b0  = (const float*)d_in[1];
    const float* b_b0  = (const float*)d_in[2];
    const float* w_b1  = (const float*)d_in[3];
    const float* b_b1  = (const float*)d_in[4];
    const float* w_n0  = (const float*)d_in[5];
    const float* b_n0  = (const float*)d_in[6];
    const float* w_n1  = (const float*)d_in[7];
    const float* b_n1  = (const float*)d_in[8];
    const float* w_sh  = (const float*)d_in[9];
    const float* b_sh  = (const float*)d_in[10];
    const float* w_hm  = (const float*)d_in[11];
    const float* b_hm  = (const float*)d_in[12];
    const float* w_reg = (const float*)d_in[13];
    const float* b_reg = (const float*)d_in[14];
    const float* w_hei = (const float*)d_in[15];
    const float* b_hei = (const float*)d_in[16];
    const float* w_dim = (const float*)d_in[17];
    const float* b_dim = (const float*)d_in[18];
    const float* w_rot = (const float*)d_in[19];
    const float* b_rot = (const float*)d_in[20];
    const float* w_vel = (const float*)d_in[21];
    const float* b_vel = (const float*)d_in[22];
    const float* w_pre = (const float*)d_in[23];
    const float* b_pre = (const float*)d_in[24];
    const float* w_qe  = (const float*)d_in[25];
    const float* b_qe  = (const float*)d_in[26];
    const float* w_qpe = (const float*)d_in[27];
    const float* b_qpe = (const float*)d_in[28];

    float* out = (float*)d_out;
    float* wsf = (float*)d_ws;

    float* x0    = wsf;
    float* x1    = x0 + (size_t)128 * HW;
    float* neck  = x1 + (size_t)256 * 8100;
    float* sh    = neck + (size_t)512 * HW;
    float* heads = sh + (size_t)NTASK * 64 * HW;
    float* hm    = heads + (size_t)NTASK * 10 * HW;
    float* qpred = hm + (size_t)NTASK * 2 * HW;
    float* qf    = qpred + 300 * 7;
    float* emb   = qf + 300 * 512;
    u64* keys    = (u64*)(emb + 300 * 224);
    u64* cand    = keys + (size_t)NTASK * 65536;
    u64* topk    = cand + (size_t)NTASK * 16 * 512;
    float* zp    = (float*)(((uintptr_t)(topk + 3008) + 63) & ~(uintptr_t)63);

    float* out_bev = out;
    float* out_qf  = out + (size_t)HW * 512;
    float* out_xyz = out + (size_t)HW * 512 + 300 * 512;

    zp_init_kernel<<<dim3(1), dim3(64), 0, stream>>>(zp);

    // block0: 256->128, n_ocb = 8 (16 oc each), grid 288 (div by 8)
    conv3x3_relu_v18<<<dim3(288), dim3(512), 0, stream>>>(
        bev, w_b0, b_b0, x0, zp, 256, 8);
    conv3x3s2_relu_v3<<<dim3(36, 16), dim3(256), 0, stream>>>(
        x0, w_b1, b_b1, x1);
    conv1x1_relu_kernel<<<dim3(127, 16), dim3(256), 0, stream>>>(
        x0, w_n0, b_n0, neck);
    deconv2x2_relu_kernel<<<dim3(32, 16), dim3(256), 0, stream>>>(
        x1, w_n1, b_n1, neck + (size_t)256 * HW);
    // shared heads: 512->384 (6 tasks x 64 oc folded), n_ocb = 24, grid 864
    conv3x3_relu_v18<<<dim3(864), dim3(512), 0, stream>>>(
        neck, w_sh, b_sh, sh, zp, 512, 24);
    heads_kernel<<<dim3(127, 6), dim3(256), 0, stream>>>(
        sh, w_hm, b_hm, w_reg, b_reg, w_hei, b_hei, w_dim, b_dim,
        w_rot, b_rot, w_vel, b_vel, hm, heads);
    nms_key_kernel<<<dim3(256, 6), dim3(256), 0, stream>>>(hm, keys);
    topk_stage1_kernel<<<dim3(16, 6), dim3(256), 0, stream>>>(keys, cand);
    topk_stage2_kernel<<<dim3(6), dim3(512), 65536, stream>>>(cand, topk);
    final_decode_kernel<<<dim3(1), dim3(256), 0, stream>>>(
        topk, heads, out_xyz, qpred);
    sample_embed_kernel<<<dim3(300), dim3(256), 0, stream>>>(
        neck, out_xyz, qpred, qf, emb);
    qfout_kernel<<<dim3(600), dim3(256), 0, stream>>>(
        qf, emb, w_qe, b_qe, w_qpe, b_qpe, out_qf);
    bev_out_kernel<<<dim3(1016), dim3(256), 0, stream>>>(
        neck, w_pre, b_pre, out_bev);
}

// Round 21
// 3582.996 us; speedup vs baseline: 1.0734x; 1.0167x over previous
//
#include <hip/hip_runtime.h>

typedef unsigned long long u64;
typedef unsigned int u32;

#define HW 32400
#define IMG 180
#define NTASK 6

__constant__ int c_nc[NTASK] = {1, 2, 2, 1, 2, 2};

// async global->LDS, 16B per lane, wave-uniform LDS base
#define GLL16(SRC, DST)                                                      \
    __builtin_amdgcn_global_load_lds(                                        \
        (const __attribute__((address_space(1))) unsigned int*)(SRC),        \
        (__attribute__((address_space(3))) unsigned int*)(DST), 16, 0, 0)

// ---------------------------------------------------------------------------
// zero page init (64 floats) — OOB staging lanes read from here
// ---------------------------------------------------------------------------
__global__ void zp_init_kernel(float* zp)
{
    zp[threadIdx.x] = 0.f;
}

// ---------------------------------------------------------------------------
// 3x3 stride-1 pad-1 conv + ReLU, v18 (PROVEN BEST: conflicts 0, 1766us,
// 40 VGPR). Strided pixel ownership x = xg+{0,8,16,24} (xg=tid&7) kills the
// 8-way input-read bank conflicts: read addr = 40y + xg + C -> bank
// (8y+xg+C)%32 -> 32 banks x 2 lanes (free, m136). GLL16 async staging
// ([3 ic][34][40] row-major, +4-col shift, zero page OOB), weights via LDS
// broadcast, 3-ic chunks double-buffered, one barrier/chunk, 512 thr,
// 16 oc (two 8-oc halves). grid.x = 36*n_ocb, XCD-swizzled.
// ---------------------------------------------------------------------------
__device__ __forceinline__ void stage_in_async3(
    const float* __restrict__ in, const float* __restrict__ zp,
    float* lds_buf, int ic0, int IC, int ty0, int tx0, int tid)
{
    int lane = tid & 63;
    int wv = tid >> 6;          // 0..7
#pragma unroll
    for (int kk = 0; kk < 2; ++kk) {
        int k = wv + kk * 8;    // 0..15; 3*1360 = 4080 words = 16 issues
        int e = k * 256 + lane * 4;       // word index, mult of 4
        if (e < 4080) {
            int ic = e / 1360;            // 0..2
            int r2 = e - ic * 1360;
            int rr = r2 / 40;
            int cc = r2 - rr * 40;        // mult of 4
            int gy = ty0 - 1 + rr;
            int gx0 = tx0 - 4 + cc;       // 16B-aligned source col
            const float* src = zp;
            if (ic0 + ic < IC && (unsigned)gy < 180u && (unsigned)gx0 < 180u)
                src = in + (size_t)(ic0 + ic) * HW + (size_t)(gy * IMG + gx0);
            GLL16(src, lds_buf + e);
        }
    }
}

__global__ __launch_bounds__(512) void conv3x3_relu_v18(
    const float* __restrict__ in, const float* __restrict__ wgt,
    const float* __restrict__ bias, float* __restrict__ out,
    const float* __restrict__ zp, int IC, int n_ocb)
{
    __shared__ float s_in[2][4080];   // 3 ic x 34 rows x 40 cols
    __shared__ float s_w[2][432];     // [ic][tap][oc] flat (3*9*16)

    int per = gridDim.x >> 3;
    int g = (blockIdx.x & 7) * per + (blockIdx.x >> 3);
    int sp = g / n_ocb;
    int ocb = g - sp * n_ocb;
    int oc0 = ocb * 16;
    int ty0 = (sp / 6) * 32, tx0 = (sp % 6) * 32;

    int tid = threadIdx.x;
    int sub = tid >> 8;          // oc half
    int t8 = tid & 255;
    int xg = t8 & 7, y = t8 >> 3;
    int sub8 = sub * 8;

    const int NC = (IC + 2) / 3;   // last chunk padded

    // weight-load thread mapping (tid < 432): wq = tid>>4 in 0..26
    int wq = tid >> 4;
    int w_ic = wq / 9, w_tap = wq - w_ic * 9, w_oc = tid & 15;
    bool w_on = tid < 432;

    float acc[4][8];
#pragma unroll
    for (int p = 0; p < 4; ++p)
#pragma unroll
        for (int o = 0; o < 8; ++o) acc[p][o] = 0.f;

    // ---- prologue: stage chunk 0 into buffer 0 ----
    {
        float wA = 0.f;
        if (w_on && w_ic < IC)
            wA = wgt[((size_t)(oc0 + w_oc) * IC + w_ic) * 9 + w_tap];
        stage_in_async3(in, zp, &s_in[0][0], 0, IC, ty0, tx0, tid);
        if (w_on) s_w[0][tid] = wA;
    }
    __syncthreads();

    for (int c = 0; c < NC; ++c) {
        int cur = c & 1;

        // ---- prefetch chunk c+1 (weights->regs, async inputs,
        //      weights->LDS) ----
        if (c + 1 < NC) {
            int nic0 = (c + 1) * 3;
            float wN = 0.f;
            if (w_on && nic0 + w_ic < IC)
                wN = wgt[((size_t)(oc0 + w_oc) * IC + nic0 + w_ic) * 9 + w_tap];
            stage_in_async3(in, zp, &s_in[cur ^ 1][0], nic0, IC, ty0, tx0, tid);
            if (w_on) s_w[cur ^ 1][tid] = wN;
        }

        // ---- compute chunk c (3 ic); strided pixels xg+{0,8,16,24} ----
        {
            const float* sbuf = &s_in[cur][0];
            const float* swb = &s_w[cur][0];
#pragma unroll
            for (int ic = 0; ic < 3; ++ic) {
#pragma unroll
                for (int dy = 0; dy < 3; ++dy) {
                    // base col for p=0,dx=0: gx = tx0+xg-1 -> LDS col xg+3
                    const float* rowb =
                        sbuf + ic * 1360 + (y + dy) * 40 + xg + 3;
#pragma unroll
                    for (int p = 0; p < 4; ++p) {
                        float v0 = rowb[8 * p + 0];
                        float v1 = rowb[8 * p + 1];
                        float v2 = rowb[8 * p + 2];
                        float vv[3] = {v0, v1, v2};
#pragma unroll
                        for (int dx = 0; dx < 3; ++dx) {
                            const float* wpp =
                                swb + (ic * 9 + dy * 3 + dx) * 16 + sub8;
                            float4 w0 = *(const float4*)(wpp + 0);
                            float4 w1 = *(const float4*)(wpp + 4);
                            float wvv[8] = {w0.x, w0.y, w0.z, w0.w,
                                            w1.x, w1.y, w1.z, w1.w};
                            float* ar = acc[p];
#pragma unroll
                            for (int o = 0; o < 8; ++o)
                                ar[o] = fmaf(vv[dx], wvv[o], ar[o]);
                        }
                    }
                }
            }
        }
        __syncthreads();   // drains async loads (issued ~full compute ago)
    }

    // ---- epilogue: bias + relu + strided scalar stores ----
    int gy = ty0 + y;
    if (gy < IMG) {
#pragma unroll
        for (int p = 0; p < 4; ++p) {
            int gxp = tx0 + xg + 8 * p;
            if (gxp < IMG) {
#pragma unroll
                for (int o = 0; o < 8; ++o) {
                    float r = acc[p][o] + bias[oc0 + sub8 + o];
                    r = r > 0.f ? r : 0.f;
                    out[(size_t)(oc0 + sub8 + o) * HW + gy * IMG + gxp] = r;
                }
            }
        }
    }
}

// ---------------------------------------------------------------------------
// 3x3 stride-2 pad-1 conv + ReLU, v2: [128][180][180] -> [256][90][90]
// ---------------------------------------------------------------------------
__global__ __launch_bounds__(256) void conv3x3s2_relu_v2(
    const float* __restrict__ in, const float* __restrict__ wgt,
    const float* __restrict__ bias, float* __restrict__ out)
{
    __shared__ float s_in[2][31][34];
    __shared__ float s_w[2][9][16];

    int sp = blockIdx.x; int ocb = blockIdx.y;
    int oty0 = (sp / 6) * 15, otx0 = (sp % 6) * 15;
    int iy0 = 2 * oty0 - 1, ix0 = 2 * otx0 - 1;
    int tid = threadIdx.x;
    int tx = tid & 15, ty = tid >> 4;
    bool active = (tx < 15) && (ty < 15);

    float acc[16];
#pragma unroll
    for (int o = 0; o < 16; ++o) acc[o] = 0.f;

    for (int ic0 = 0; ic0 < 128; ic0 += 2) {
        __syncthreads();
        for (int e = tid; e < 2 * 31 * 31; e += 256) {
            int ic = e / 961; int rem = e - ic * 961;
            int rr = rem / 31; int cc = rem - rr * 31;
            int gy = iy0 + rr, gx = ix0 + cc;
            float v = 0.f;
            if ((unsigned)gy < 180u && (unsigned)gx < 180u)
                v = in[(size_t)(ic0 + ic) * HW + gy * IMG + gx];
            s_in[ic][rr][cc] = v;
        }
        for (int e = tid; e < 288; e += 256) {
            int oc = e & 15; int tap = (e >> 4) % 9; int ic = e / 144;
            s_w[ic][tap][oc] =
                wgt[((size_t)(ocb * 16 + oc) * 128 + ic0 + ic) * 9 + tap];
        }
        __syncthreads();
        if (!active) continue;
#pragma unroll
        for (int ic = 0; ic < 2; ++ic) {
#pragma unroll
            for (int tap = 0; tap < 9; ++tap) {
                int dy = tap / 3, dx = tap - dy * 3;
                float v = s_in[ic][2 * ty + dy][2 * tx + dx];
                float4 w0 = *(const float4*)&s_w[ic][tap][0];
                float4 w1 = *(const float4*)&s_w[ic][tap][4];
                float4 w2 = *(const float4*)&s_w[ic][tap][8];
                float4 w3 = *(const float4*)&s_w[ic][tap][12];
                float wv[16] = {w0.x, w0.y, w0.z, w0.w, w1.x, w1.y, w1.z, w1.w,
                                w2.x, w2.y, w2.z, w2.w, w3.x, w3.y, w3.z, w3.w};
#pragma unroll
                for (int o = 0; o < 16; ++o) acc[o] = fmaf(v, wv[o], acc[o]);
            }
        }
    }
    if (active) {
        int yy = oty0 + ty, xx = otx0 + tx;
#pragma unroll
        for (int o = 0; o < 16; ++o) {
            float r = acc[o] + bias[ocb * 16 + o];
            out[(size_t)(ocb * 16 + o) * 8100 + yy * 90 + xx] =
                r > 0.f ? r : 0.f;
        }
    }
}

// ---------------------------------------------------------------------------
// 1x1 conv 128->256 + ReLU (writes neck channels 0..255)
// ---------------------------------------------------------------------------
__global__ __launch_bounds__(256) void conv1x1_relu_kernel(
    const float* __restrict__ in, const float* __restrict__ w,
    const float* __restrict__ bias, float* __restrict__ out)
{
    __shared__ float s_x[8][256];
    __shared__ float s_w[8][16];
    int p0 = blockIdx.x * 256; int ocb = blockIdx.y;
    int tid = threadIdx.x;
    float acc[16];
#pragma unroll
    for (int o = 0; o < 16; ++o) acc[o] = 0.f;

    for (int ic0 = 0; ic0 < 128; ic0 += 8) {
        for (int e = tid; e < 2048; e += 256) {
            int ic = e >> 8; int p = e & 255;
            s_x[ic][p] = (p0 + p < HW) ? in[(size_t)(ic0 + ic) * HW + p0 + p] : 0.f;
        }
        for (int e = tid; e < 128; e += 256) {
            int ic = e >> 4; int oc = e & 15;
            s_w[ic][oc] = w[(size_t)(ocb * 16 + oc) * 128 + ic0 + ic];
        }
        __syncthreads();
#pragma unroll
        for (int ic = 0; ic < 8; ++ic) {
            float v = s_x[ic][tid];
            float4 w0 = *(const float4*)&s_w[ic][0];
            float4 w1 = *(const float4*)&s_w[ic][4];
            float4 w2 = *(const float4*)&s_w[ic][8];
            float4 w3 = *(const float4*)&s_w[ic][12];
            float wv[16] = {w0.x, w0.y, w0.z, w0.w, w1.x, w1.y, w1.z, w1.w,
                            w2.x, w2.y, w2.z, w2.w, w3.x, w3.y, w3.z, w3.w};
#pragma unroll
            for (int o = 0; o < 16; ++o) acc[o] = fmaf(v, wv[o], acc[o]);
        }
        __syncthreads();
    }
    int p = p0 + tid;
    if (p < HW) {
#pragma unroll
        for (int o = 0; o < 16; ++o) {
            float r = acc[o] + bias[ocb * 16 + o];
            out[(size_t)(ocb * 16 + o) * HW + p] = r > 0.f ? r : 0.f;
        }
    }
}

// ---------------------------------------------------------------------------
// 2x2 stride-2 transposed conv + ReLU: x1[256][90][90] -> neck ch 256..511
// ---------------------------------------------------------------------------
__global__ __launch_bounds__(256) void deconv2x2_relu_kernel(
    const float* __restrict__ in, const float* __restrict__ wgt,
    const float* __restrict__ bias, float* __restrict__ out)
{
    __shared__ float s_x[8][256];
    __shared__ float s_w[8][4][16];
    int p0 = blockIdx.x * 256; int ocb = blockIdx.y;
    int tid = threadIdx.x;
    float acc[4][16];
#pragma unroll
    for (int ab = 0; ab < 4; ++ab)
#pragma unroll
        for (int o = 0; o < 16; ++o) acc[ab][o] = 0.f;

    for (int ic0 = 0; ic0 < 256; ic0 += 8) {
        for (int e = tid; e < 2048; e += 256) {
            int ic = e >> 8; int p = e & 255;
            s_x[ic][p] = (p0 + p < 8100) ? in[(size_t)(ic0 + ic) * 8100 + p0 + p] : 0.f;
        }
        for (int e = tid; e < 512; e += 256) {
            int oc = e & 15; int ab = (e >> 4) & 3; int ic = e >> 6;
            s_w[ic][ab][oc] =
                wgt[((size_t)(ocb * 16 + oc) * 256 + ic0 + ic) * 4 + ab];
        }
        __syncthreads();
#pragma unroll
        for (int ic = 0; ic < 8; ++ic) {
            float v = s_x[ic][tid];
#pragma unroll
            for (int ab = 0; ab < 4; ++ab) {
                float4 w0 = *(const float4*)&s_w[ic][ab][0];
                float4 w1 = *(const float4*)&s_w[ic][ab][4];
                float4 w2 = *(const float4*)&s_w[ic][ab][8];
                float4 w3 = *(const float4*)&s_w[ic][ab][12];
                float wv[16] = {w0.x, w0.y, w0.z, w0.w, w1.x, w1.y, w1.z, w1.w,
                                w2.x, w2.y, w2.z, w2.w, w3.x, w3.y, w3.z, w3.w};
#pragma unroll
                for (int o = 0; o < 16; ++o)
                    acc[ab][o] = fmaf(v, wv[o], acc[ab][o]);
            }
        }
        __syncthreads();
    }
    int sp = p0 + tid;
    if (sp < 8100) {
        int sy = sp / 90, sx = sp - sy * 90;
#pragma unroll
        for (int ab = 0; ab < 4; ++ab) {
            int a = ab >> 1, bb = ab & 1;
            int Y = 2 * sy + a, X = 2 * sx + bb;
#pragma unroll
            for (int o = 0; o < 16; ++o) {
                float r = acc[ab][o] + bias[ocb * 16 + o];
                out[(size_t)(ocb * 16 + o) * HW + Y * IMG + X] = r > 0.f ? r : 0.f;
            }
        }
    }
}

// ---------------------------------------------------------------------------
// Per-pixel 1x1 heads (12 outputs from 64 ch) + sigmoid on hm channels.
// ---------------------------------------------------------------------------
__global__ __launch_bounds__(256) void heads_kernel(
    const float* __restrict__ sh,
    const float* __restrict__ w_hm, const float* __restrict__ b_hm,
    const float* __restrict__ w_reg, const float* __restrict__ b_reg,
    const float* __restrict__ w_hei, const float* __restrict__ b_hei,
    const float* __restrict__ w_dim, const float* __restrict__ b_dim,
    const float* __restrict__ w_rot, const float* __restrict__ b_rot,
    const float* __restrict__ w_vel, const float* __restrict__ b_vel,
    float* __restrict__ hm_sig, float* __restrict__ heads)
{
    __shared__ float s_w[64][12];
    __shared__ float s_b[12];
    int t = blockIdx.y;
    int tid = threadIdx.x;
    for (int e = tid; e < 768; e += 256) {
        int c = e / 12; int r = e - c * 12;
        float v;
        if (r < 2)       v = w_hm [(t * 2 + r) * 64 + c];
        else if (r < 4)  v = w_reg[(t * 2 + r - 2) * 64 + c];
        else if (r < 5)  v = w_hei[t * 64 + c];
        else if (r < 8)  v = w_dim[(t * 3 + r - 5) * 64 + c];
        else if (r < 10) v = w_rot[(t * 2 + r - 8) * 64 + c];
        else             v = w_vel[(t * 2 + r - 10) * 64 + c];
        s_w[c][r] = v;
    }
    if (tid < 12) {
        int r = tid; float v;
        if (r < 2)       v = b_hm [t * 2 + r];
        else if (r < 4)  v = b_reg[t * 2 + r - 2];
        else if (r < 5)  v = b_hei[t];
        else if (r < 8)  v = b_dim[t * 3 + r - 5];
        else if (r < 10) v = b_rot[t * 2 + r - 8];
        else             v = b_vel[t * 2 + r - 10];
        s_b[r] = v;
    }
    __syncthreads();
    int p = blockIdx.x * 256 + tid;
    if (p >= HW) return;
    float a[12];
#pragma unroll
    for (int r = 0; r < 12; ++r) a[r] = 0.f;
    const float* shp = sh + (size_t)t * 64 * HW + p;
    for (int c = 0; c < 64; ++c) {
        float x = shp[(size_t)c * HW];
        float4 w0 = *(const float4*)&s_w[c][0];
        float4 w1 = *(const float4*)&s_w[c][4];
        float4 w2 = *(const float4*)&s_w[c][8];
        float wv[12] = {w0.x, w0.y, w0.z, w0.w, w1.x, w1.y, w1.z, w1.w,
                        w2.x, w2.y, w2.z, w2.w};
#pragma unroll
        for (int r = 0; r < 12; ++r) a[r] = fmaf(x, wv[r], a[r]);
    }
#pragma unroll
    for (int r = 0; r < 12; ++r) a[r] += s_b[r];
    hm_sig[(size_t)(t * 2 + 0) * HW + p] = 1.f / (1.f + expf(-a[0]));
    hm_sig[(size_t)(t * 2 + 1) * HW + p] = 1.f / (1.f + expf(-a[1]));
#pragma unroll
    for (int r = 0; r < 10; ++r)
        heads[(size_t)(t * 10 + r) * HW + p] = a[2 + r];
}

// ---------------------------------------------------------------------------
// 3x3 max-pool NMS -> packed sort keys (score_bits<<32 | ~combined_idx)
// ---------------------------------------------------------------------------
__global__ __launch_bounds__(256) void nms_key_kernel(
    const float* __restrict__ hm_sig, u64* __restrict__ keys)
{
    int t = blockIdx.y;
    int i = blockIdx.x * 256 + threadIdx.x;   // < 65536
    int nc = c_nc[t];
    u64 key = 0;
    if (i < nc * HW) {
        int c = i / HW; int p = i - c * HW;
        int y = p / IMG; int x = p - y * IMG;
        const float* base = hm_sig + (size_t)(t * 2 + c) * HW;
        float s = base[p];
        float m = s;
#pragma unroll
        for (int dy = -1; dy <= 1; ++dy)
#pragma unroll
            for (int dx = -1; dx <= 1; ++dx) {
                int yy = y + dy, xx = x + dx;
                if ((unsigned)yy < 180u && (unsigned)xx < 180u)
                    m = fmaxf(m, base[yy * IMG + xx]);
            }
        float sm = (s == m) ? s : 0.f;
        key = ((u64)__float_as_uint(sm) << 32) | (u64)(u32)(~(u32)i);
    }
    keys[(size_t)t * 65536 + i] = key;
}

// ---------------------------------------------------------------------------
// Bitonic sort (descending) of N u64 keys in LDS, T threads.
// ---------------------------------------------------------------------------
template <int N, int T>
__device__ void bitonic_sort_desc(u64* s)
{
    const int tid = threadIdx.x;
    for (int k = 2; k <= N; k <<= 1) {
        for (int j = k >> 1; j > 0; j >>= 1) {
            __syncthreads();
            for (int idx = tid; idx < N / 2; idx += T) {
                int i = ((idx & ~(j - 1)) << 1) | (idx & (j - 1));
                int l = i | j;
                u64 a = s[i], b = s[l];
                bool sw = ((i & k) == 0) ? (a < b) : (a > b);
                if (sw) { s[i] = b; s[l] = a; }
            }
        }
    }
    __syncthreads();
}

__global__ __launch_bounds__(256) void topk_stage1_kernel(
    const u64* __restrict__ keys, u64* __restrict__ cand)
{
    __shared__ u64 s[4096];
    int t = blockIdx.y, ch = blockIdx.x;
    const u64* src = keys + (size_t)t * 65536 + ch * 4096;
    for (int i = threadIdx.x; i < 4096; i += 256) s[i] = src[i];
    bitonic_sort_desc<4096, 256>(s);
    u64* dst = cand + ((size_t)t * 16 + ch) * 512;
    for (int i = threadIdx.x; i < 512; i += 256) dst[i] = s[i];
}

__global__ __launch_bounds__(512) void topk_stage2_kernel(
    const u64* __restrict__ cand, u64* __restrict__ top_keys)
{
    extern __shared__ u64 s2[];
    int t = blockIdx.x;
    for (int i = threadIdx.x; i < 8192; i += 512) s2[i] = cand[(size_t)t * 8192 + i];
    bitonic_sort_desc<8192, 512>(s2);
    for (int i = threadIdx.x; i < 500; i += 512) top_keys[t * 500 + i] = s2[i];
}

// ---------------------------------------------------------------------------
// Final top-300 over 3000 candidates + box decode.
// ---------------------------------------------------------------------------
__global__ __launch_bounds__(256) void final_decode_kernel(
    const u64* __restrict__ top_keys, const float* __restrict__ heads,
    float* __restrict__ qxyz, float* __restrict__ qpred)
{
    __shared__ u64 s[4096];
    int tid = threadIdx.x;
    for (int i = tid; i < 4096; i += 256) {
        u64 v = 0;
        if (i < 3000) {
            u64 k = top_keys[i];
            v = (k & 0xFFFFFFFF00000000ull) | (u64)(u32)(~(u32)i);
        }
        s[i] = v;
    }
    bitonic_sort_desc<4096, 256>(s);
    for (int q = tid; q < 300; q += 256) {
        u64 k2 = s[q];
        u32 gpos = ~(u32)(k2 & 0xFFFFFFFFull);
        int t = gpos / 500;
        u64 ok = top_keys[gpos];
        float score = __uint_as_float((u32)(ok >> 32));
        u32 comb = ~(u32)(ok & 0xFFFFFFFFull);
        int p = (int)(comb % HW);
        int yy = p / IMG, xx = p - yy * IMG;
        const float* hd = heads + (size_t)t * 10 * HW;
        float reg0 = hd[0 * HW + p], reg1 = hd[1 * HW + p], hei = hd[2 * HW + p];
        float d0 = expf(hd[3 * HW + p]);
        float d1 = expf(hd[4 * HW + p]);
        float d2 = expf(hd[5 * HW + p]);
        float rot0 = hd[6 * HW + p], rot1 = hd[7 * HW + p];
        float vel0 = hd[8 * HW + p], vel1 = hd[9 * HW + p];
        float yaw = atan2f(rot0, rot1);
        float X = ((float)xx + reg0) * 8.0f * 0.075f + (-54.0f);
        float Y = ((float)yy + reg1) * 8.0f * 0.075f + (-54.0f);
        qxyz[q * 3 + 0] = X;
        qxyz[q * 3 + 1] = Y;
        qxyz[q * 3 + 2] = hei;
        qpred[q * 7 + 0] = d0; qpred[q * 7 + 1] = d1; qpred[q * 7 + 2] = d2;
        qpred[q * 7 + 3] = yaw; qpred[q * 7 + 4] = vel0; qpred[q * 7 + 5] = vel1;
        qpred[q * 7 + 6] = score;
    }
}

// ---------------------------------------------------------------------------
// Bilinear grid sample of neck at 300 queries + positional embedding.
// ---------------------------------------------------------------------------
__global__ __launch_bounds__(256) void sample_embed_kernel(
    const float* __restrict__ neck, const float* __restrict__ qxyz,
    const float* __restrict__ qpred, float* __restrict__ qf,
    float* __restrict__ emb)
{
    int q = blockIdx.x;
    int tid = threadIdx.x;
    float X = qxyz[q * 3 + 0], Y = qxyz[q * 3 + 1];
    float xn = (X - (-54.0f)) / 108.0f * 2.0f - 1.0f;
    float yn = (Y - (-54.0f)) / 108.0f * 2.0f - 1.0f;
    float gx = (xn + 1.0f) * 180.0f / 2.0f - 0.5f;
    float gy = (yn + 1.0f) * 180.0f / 2.0f - 0.5f;
    float x0f = floorf(gx), y0f = floorf(gy);
    float wx = gx - x0f, wy = gy - y0f;
    int x0 = (int)x0f, y0 = (int)y0f;
    int xs[4] = {x0, x0 + 1, x0, x0 + 1};
    int ys[4] = {y0, y0, y0 + 1, y0 + 1};
    float wt[4] = {(1.f - wx) * (1.f - wy), wx * (1.f - wy),
                   (1.f - wx) * wy, wx * wy};
    int idx[4]; float wv[4];
#pragma unroll
    for (int k = 0; k < 4; ++k) {
        bool valid = xs[k] >= 0 && xs[k] < IMG && ys[k] >= 0 && ys[k] < IMG;
        int cx = xs[k] < 0 ? 0 : (xs[k] > IMG - 1 ? IMG - 1 : xs[k]);
        int cy = ys[k] < 0 ? 0 : (ys[k] > IMG - 1 ? IMG - 1 : ys[k]);
        idx[k] = cy * IMG + cx;
        wv[k] = valid ? wt[k] : 0.f;
    }
    for (int c = tid; c < 512; c += 256) {
        const float* f = neck + (size_t)c * HW;
        float v = f[idx[0]] * wv[0] + f[idx[1]] * wv[1] +
                  f[idx[2]] * wv[2] + f[idx[3]] * wv[3];
        qf[q * 512 + c] = v;
    }
    if (tid < 224) {
        int fidx = tid >> 5; int j = tid & 31; int m = j >> 1;
        float pos = qpred[q * 7 + fidx] * 6.283185307179586f;
        float dt = 2.0f * (float)m / 32.0f + 1.0f;
        float v = pos / dt;
        emb[q * 224 + tid] = (j & 1) ? cosf(v) : sinf(v);
    }
}

// ---------------------------------------------------------------------------
// qf_out = qf @ w_qe^T + b_qe + qf + emb @ w_qpe^T + b_qpe
// ---------------------------------------------------------------------------
__global__ __launch_bounds__(256) void qfout_kernel(
    const float* __restrict__ qf, const float* __restrict__ emb,
    const float* __restrict__ w_qe, const float* __restrict__ b_qe,
    const float* __restrict__ w_qpe, const float* __restrict__ b_qpe,
    float* __restrict__ outq)
{
    int g = blockIdx.x * 256 + threadIdx.x;
    if (g >= 300 * 512) return;
    int q = g >> 9, o = g & 511;
    const float* qrow = qf + q * 512;
    const float* wrow = w_qe + (size_t)o * 512;
    float acc = 0.f;
    for (int c = 0; c < 512; ++c) acc = fmaf(qrow[c], wrow[c], acc);
    const float* erow = emb + q * 224;
    const float* wr2 = w_qpe + (size_t)o * 224;
    float acc2 = 0.f;
    for (int j = 0; j < 224; ++j) acc2 = fmaf(erow[j], wr2[j], acc2);
    outq[g] = acc + b_qe[o] + qrow[o] + acc2 + b_qpe[o];
}

// ---------------------------------------------------------------------------
// bev_out[p][o] = sum_c neck[c][p] * w_pre[o][c] + b_pre[o] + neck[o][p]
// ---------------------------------------------------------------------------
__global__ __launch_bounds__(256) void bev_out_kernel(
    const float* __restrict__ neck, const float* __restrict__ w_pre,
    const float* __restrict__ b_pre, float* __restrict__ outb)
{
    __shared__ float sA[16][132];
    __shared__ float sB[16][132];
    int per = gridDim.x >> 3;
    int g = (blockIdx.x & 7) * per + (blockIdx.x >> 3);
    int pt = g >> 2; int ob = g & 3;
    int p0 = pt * 128, o0 = ob * 128;
    int tid = threadIdx.x, tx = tid & 15, ty = tid >> 4;
    float acc[8][8];
#pragma unroll
    for (int i = 0; i < 8; ++i)
#pragma unroll
        for (int j = 0; j < 8; ++j) acc[i][j] = 0.f;

    for (int c0 = 0; c0 < 512; c0 += 16) {
        for (int e = tid; e < 2048; e += 256) {
            int k = e >> 7, p = e & 127;
            int gp = p0 + p;
            sA[k][p] = gp < HW ? neck[(size_t)(c0 + k) * HW + gp] : 0.f;
        }
        for (int e4 = tid; e4 < 512; e4 += 256) {
            int o = e4 >> 2, kk = e4 & 3;
            float4 v = *(const float4*)&w_pre[(size_t)(o0 + o) * 512 + c0 + kk * 4];
            sB[kk * 4 + 0][o] = v.x; sB[kk * 4 + 1][o] = v.y;
            sB[kk * 4 + 2][o] = v.z; sB[kk * 4 + 3][o] = v.w;
        }
        __syncthreads();
#pragma unroll
        for (int k = 0; k < 16; ++k) {
            float4 a0 = *(const float4*)&sA[k][ty * 4];
            float4 a1 = *(const float4*)&sA[k][64 + ty * 4];
            float4 b0 = *(const float4*)&sB[k][tx * 4];
            float4 b1 = *(const float4*)&sB[k][64 + tx * 4];
            float av[8] = {a0.x, a0.y, a0.z, a0.w, a1.x, a1.y, a1.z, a1.w};
            float bv[8] = {b0.x, b0.y, b0.z, b0.w, b1.x, b1.y, b1.z, b1.w};
#pragma unroll
            for (int i = 0; i < 8; ++i)
#pragma unroll
                for (int j = 0; j < 8; ++j)
                    acc[i][j] = fmaf(av[i], bv[j], acc[i][j]);
        }
        __syncthreads();
    }
#pragma unroll
    for (int i = 0; i < 8; ++i) {
        int pl = (i < 4) ? (ty * 4 + i) : (64 + ty * 4 + i - 4);
        int p = p0 + pl;
        if (p >= HW) continue;
#pragma unroll
        for (int j = 0; j < 8; ++j) {
            int ol = (j < 4) ? (tx * 4 + j) : (64 + tx * 4 + j - 4);
            int o = o0 + ol;
            outb[(size_t)p * 512 + o] =
                acc[i][j] + b_pre[o] + neck[(size_t)o * HW + p];
        }
    }
}

// ---------------------------------------------------------------------------
extern "C" void kernel_launch(void* const* d_in, const int* in_sizes, int n_in,
                              void* d_out, int out_size, void* d_ws, size_t ws_size,
                              hipStream_t stream)
{
    (void)in_sizes; (void)n_in; (void)out_size; (void)ws_size;

    const float* bev   = (const float*)d_in[0];
    const float* w_b0  = (const float*)d_in[1];
    const float* b_b0  = (const float*)d_in[2];
    const float* w_b1  = (const float*)d_in[3];
    const float* b_b1  = (const float*)d_in[4];
    const float* w_n0  = (const float*)d_in[5];
    const float* b_n0  = (const float*)d_in[6];
    const float* w_n1  = (const float*)d_in[7];
    const float* b_n1  = (const float*)d_in[8];
    const float* w_sh  = (const float*)d_in[9];
    const float* b_sh  = (const float*)d_in[10];
    const float* w_hm  = (const float*)d_in[11];
    const float* b_hm  = (const float*)d_in[12];
    const float* w_reg = (const float*)d_in[13];
    const float* b_reg = (const float*)d_in[14];
    const float* w_hei = (const float*)d_in[15];
    const float* b_hei = (const float*)d_in[16];
    const float* w_dim = (const float*)d_in[17];
    const float* b_dim = (const float*)d_in[18];
    const float* w_rot = (const float*)d_in[19];
    const float* b_rot = (const float*)d_in[20];
    const float* w_vel = (const float*)d_in[21];
    const float* b_vel = (const float*)d_in[22];
    const float* w_pre = (const float*)d_in[23];
    const float* b_pre = (const float*)d_in[24];
    const float* w_qe  = (const float*)d_in[25];
    const float* b_qe  = (const float*)d_in[26];
    const float* w_qpe = (const float*)d_in[27];
    const float* b_qpe = (const float*)d_in[28];

    float* out = (float*)d_out;
    float* wsf = (float*)d_ws;

    float* x0    = wsf;
    float* x1    = x0 + (size_t)128 * HW;
    float* neck  = x1 + (size_t)256 * 8100;
    float* sh    = neck + (size_t)512 * HW;
    float* heads = sh + (size_t)NTASK * 64 * HW;
    float* hm    = heads + (size_t)NTASK * 10 * HW;
    float* qpred = hm + (size_t)NTASK * 2 * HW;
    float* qf    = qpred + 300 * 7;
    float* emb   = qf + 300 * 512;
    u64* keys    = (u64*)(emb + 300 * 224);
    u64* cand    = keys + (size_t)NTASK * 65536;
    u64* topk    = cand + (size_t)NTASK * 16 * 512;
    float* zp    = (float*)(((uintptr_t)(topk + 3008) + 63) & ~(uintptr_t)63);

    float* out_bev = out;
    float* out_qf  = out + (size_t)HW * 512;
    float* out_xyz = out + (size_t)HW * 512 + 300 * 512;

    zp_init_kernel<<<dim3(1), dim3(64), 0, stream>>>(zp);

    // block0: 256->128, n_ocb = 8 (16 oc each), grid 288 (div by 8)
    conv3x3_relu_v18<<<dim3(288), dim3(512), 0, stream>>>(
        bev, w_b0, b_b0, x0, zp, 256, 8);
    conv3x3s2_relu_v2<<<dim3(36, 16), dim3(256), 0, stream>>>(
        x0, w_b1, b_b1, x1);
    conv1x1_relu_kernel<<<dim3(127, 16), dim3(256), 0, stream>>>(
        x0, w_n0, b_n0, neck);
    deconv2x2_relu_kernel<<<dim3(32, 16), dim3(256), 0, stream>>>(
        x1, w_n1, b_n1, neck + (size_t)256 * HW);
    // shared heads: 512->384 (6 tasks x 64 oc folded), n_ocb = 24, grid 864
    conv3x3_relu_v18<<<dim3(864), dim3(512), 0, stream>>>(
        neck, w_sh, b_sh, sh, zp, 512, 24);
    heads_kernel<<<dim3(127, 6), dim3(256), 0, stream>>>(
        sh, w_hm, b_hm, w_reg, b_reg, w_hei, b_hei, w_dim, b_dim,
        w_rot, b_rot, w_vel, b_vel, hm, heads);
    nms_key_kernel<<<dim3(256, 6), dim3(256), 0, stream>>>(hm, keys);
    topk_stage1_kernel<<<dim3(16, 6), dim3(256), 0, stream>>>(keys, cand);
    topk_stage2_kernel<<<dim3(6), dim3(512), 65536, stream>>>(cand, topk);
    final_decode_kernel<<<dim3(1), dim3(256), 0, stream>>>(
        topk, heads, out_xyz, qpred);
    sample_embed_kernel<<<dim3(300), dim3(256), 0, stream>>>(
        neck, out_xyz, qpred, qf, emb);
    qfout_kernel<<<dim3(600), dim3(256), 0, stream>>>(
        qf, emb, w_qe, b_qe, w_qpe, b_qpe, out_qf);
    bev_out_kernel<<<dim3(1016), dim3(256), 0, stream>>>(
        neck, w_pre, b_pre, out_bev);
}

// Round 22
// 3560.099 us; speedup vs baseline: 1.0804x; 1.0064x over previous
//
#include <hip/hip_runtime.h>

typedef unsigned long long u64;
typedef unsigned int u32;

#define HW 32400
#define IMG 180
#define NTASK 6

__constant__ int c_nc[NTASK] = {1, 2, 2, 1, 2, 2};

// async global->LDS, 16B per lane, wave-uniform LDS base
#define GLL16(SRC, DST)                                                      \
    __builtin_amdgcn_global_load_lds(                                        \
        (const __attribute__((address_space(1))) unsigned int*)(SRC),        \
        (__attribute__((address_space(3))) unsigned int*)(DST), 16, 0, 0)

// ---------------------------------------------------------------------------
// zero page init (64 floats) — OOB staging lanes read from here
// ---------------------------------------------------------------------------
__global__ void zp_init_kernel(float* zp)
{
    zp[threadIdx.x] = 0.f;
}

// ---------------------------------------------------------------------------
// 3x3 stride-1 pad-1 conv + ReLU, v21 = v18 (conflicts 0, 1766us, 40 VGPR)
// with the p/dx loops SWAPPED so each (ic,dy,dx) weight pair is loaded ONCE:
// weight b128 broadcasts drop 24 -> 6 per (ic,dy) (216 -> 54 per chunk).
// At 40 VGPR v18 demonstrably re-loaded weights per p; the LDS pipe
// (~650cy/wave-chunk x 32 waves > 13.8k FMA span/SIMD) was still the
// co-limiter despite zero conflicts. Input reads unchanged (12 b32/(ic,dy),
// same conflict-free set: bank (8y+xg+C)%32 = 2 lanes each). FMAs identical.
// GLL16 async staging, zero page OOB, 3-ic chunks double-buffered, one
// barrier/chunk, 512 thr, 16 oc (two 8-oc halves). grid.x=36*n_ocb, XCD-swz.
// ---------------------------------------------------------------------------
__device__ __forceinline__ void stage_in_async3(
    const float* __restrict__ in, const float* __restrict__ zp,
    float* lds_buf, int ic0, int IC, int ty0, int tx0, int tid)
{
    int lane = tid & 63;
    int wv = tid >> 6;          // 0..7
#pragma unroll
    for (int kk = 0; kk < 2; ++kk) {
        int k = wv + kk * 8;    // 0..15; 3*1360 = 4080 words = 16 issues
        int e = k * 256 + lane * 4;       // word index, mult of 4
        if (e < 4080) {
            int ic = e / 1360;            // 0..2
            int r2 = e - ic * 1360;
            int rr = r2 / 40;
            int cc = r2 - rr * 40;        // mult of 4
            int gy = ty0 - 1 + rr;
            int gx0 = tx0 - 4 + cc;       // 16B-aligned source col
            const float* src = zp;
            if (ic0 + ic < IC && (unsigned)gy < 180u && (unsigned)gx0 < 180u)
                src = in + (size_t)(ic0 + ic) * HW + (size_t)(gy * IMG + gx0);
            GLL16(src, lds_buf + e);
        }
    }
}

__global__ __launch_bounds__(512) void conv3x3_relu_v21(
    const float* __restrict__ in, const float* __restrict__ wgt,
    const float* __restrict__ bias, float* __restrict__ out,
    const float* __restrict__ zp, int IC, int n_ocb)
{
    __shared__ float s_in[2][4080];   // 3 ic x 34 rows x 40 cols
    __shared__ float s_w[2][432];     // [ic][tap][oc] flat (3*9*16)

    int per = gridDim.x >> 3;
    int g = (blockIdx.x & 7) * per + (blockIdx.x >> 3);
    int sp = g / n_ocb;
    int ocb = g - sp * n_ocb;
    int oc0 = ocb * 16;
    int ty0 = (sp / 6) * 32, tx0 = (sp % 6) * 32;

    int tid = threadIdx.x;
    int sub = tid >> 8;          // oc half
    int t8 = tid & 255;
    int xg = t8 & 7, y = t8 >> 3;
    int sub8 = sub * 8;

    const int NC = (IC + 2) / 3;   // last chunk padded

    // weight-load thread mapping (tid < 432): wq = tid>>4 in 0..26
    int wq = tid >> 4;
    int w_ic = wq / 9, w_tap = wq - w_ic * 9, w_oc = tid & 15;
    bool w_on = tid < 432;

    float acc[4][8];
#pragma unroll
    for (int p = 0; p < 4; ++p)
#pragma unroll
        for (int o = 0; o < 8; ++o) acc[p][o] = 0.f;

    // ---- prologue: stage chunk 0 into buffer 0 ----
    {
        float wA = 0.f;
        if (w_on && w_ic < IC)
            wA = wgt[((size_t)(oc0 + w_oc) * IC + w_ic) * 9 + w_tap];
        stage_in_async3(in, zp, &s_in[0][0], 0, IC, ty0, tx0, tid);
        if (w_on) s_w[0][tid] = wA;
    }
    __syncthreads();

    for (int c = 0; c < NC; ++c) {
        int cur = c & 1;

        // ---- prefetch chunk c+1 (weights->regs, async inputs,
        //      weights->LDS) ----
        if (c + 1 < NC) {
            int nic0 = (c + 1) * 3;
            float wN = 0.f;
            if (w_on && nic0 + w_ic < IC)
                wN = wgt[((size_t)(oc0 + w_oc) * IC + nic0 + w_ic) * 9 + w_tap];
            stage_in_async3(in, zp, &s_in[cur ^ 1][0], nic0, IC, ty0, tx0, tid);
            if (w_on) s_w[cur ^ 1][tid] = wN;
        }

        // ---- compute chunk c (3 ic); dx outer, weights loaded once ----
        {
            const float* sbuf = &s_in[cur][0];
            const float* swb = &s_w[cur][0];
#pragma unroll
            for (int ic = 0; ic < 3; ++ic) {
#pragma unroll
                for (int dy = 0; dy < 3; ++dy) {
                    // base col for p=0,dx=0: gx = tx0+xg-1 -> LDS col xg+3
                    const float* rowb =
                        sbuf + ic * 1360 + (y + dy) * 40 + xg + 3;
#pragma unroll
                    for (int dx = 0; dx < 3; ++dx) {
                        const float* wpp =
                            swb + (ic * 9 + dy * 3 + dx) * 16 + sub8;
                        float4 w0 = *(const float4*)(wpp + 0);
                        float4 w1 = *(const float4*)(wpp + 4);
                        float wvv[8] = {w0.x, w0.y, w0.z, w0.w,
                                        w1.x, w1.y, w1.z, w1.w};
#pragma unroll
                        for (int p = 0; p < 4; ++p) {
                            float vv = rowb[8 * p + dx];
                            float* ar = acc[p];
#pragma unroll
                            for (int o = 0; o < 8; ++o)
                                ar[o] = fmaf(vv, wvv[o], ar[o]);
                        }
                    }
                }
            }
        }
        __syncthreads();   // drains async loads (issued ~full compute ago)
    }

    // ---- epilogue: bias + relu + strided scalar stores ----
    int gy = ty0 + y;
    if (gy < IMG) {
#pragma unroll
        for (int p = 0; p < 4; ++p) {
            int gxp = tx0 + xg + 8 * p;
            if (gxp < IMG) {
#pragma unroll
                for (int o = 0; o < 8; ++o) {
                    float r = acc[p][o] + bias[oc0 + sub8 + o];
                    r = r > 0.f ? r : 0.f;
                    out[(size_t)(oc0 + sub8 + o) * HW + gy * IMG + gxp] = r;
                }
            }
        }
    }
}

// ---------------------------------------------------------------------------
// 3x3 stride-2 pad-1 conv + ReLU, v2: [128][180][180] -> [256][90][90]
// ---------------------------------------------------------------------------
__global__ __launch_bounds__(256) void conv3x3s2_relu_v2(
    const float* __restrict__ in, const float* __restrict__ wgt,
    const float* __restrict__ bias, float* __restrict__ out)
{
    __shared__ float s_in[2][31][34];
    __shared__ float s_w[2][9][16];

    int sp = blockIdx.x; int ocb = blockIdx.y;
    int oty0 = (sp / 6) * 15, otx0 = (sp % 6) * 15;
    int iy0 = 2 * oty0 - 1, ix0 = 2 * otx0 - 1;
    int tid = threadIdx.x;
    int tx = tid & 15, ty = tid >> 4;
    bool active = (tx < 15) && (ty < 15);

    float acc[16];
#pragma unroll
    for (int o = 0; o < 16; ++o) acc[o] = 0.f;

    for (int ic0 = 0; ic0 < 128; ic0 += 2) {
        __syncthreads();
        for (int e = tid; e < 2 * 31 * 31; e += 256) {
            int ic = e / 961; int rem = e - ic * 961;
            int rr = rem / 31; int cc = rem - rr * 31;
            int gy = iy0 + rr, gx = ix0 + cc;
            float v = 0.f;
            if ((unsigned)gy < 180u && (unsigned)gx < 180u)
                v = in[(size_t)(ic0 + ic) * HW + gy * IMG + gx];
            s_in[ic][rr][cc] = v;
        }
        for (int e = tid; e < 288; e += 256) {
            int oc = e & 15; int tap = (e >> 4) % 9; int ic = e / 144;
            s_w[ic][tap][oc] =
                wgt[((size_t)(ocb * 16 + oc) * 128 + ic0 + ic) * 9 + tap];
        }
        __syncthreads();
        if (!active) continue;
#pragma unroll
        for (int ic = 0; ic < 2; ++ic) {
#pragma unroll
            for (int tap = 0; tap < 9; ++tap) {
                int dy = tap / 3, dx = tap - dy * 3;
                float v = s_in[ic][2 * ty + dy][2 * tx + dx];
                float4 w0 = *(const float4*)&s_w[ic][tap][0];
                float4 w1 = *(const float4*)&s_w[ic][tap][4];
                float4 w2 = *(const float4*)&s_w[ic][tap][8];
                float4 w3 = *(const float4*)&s_w[ic][tap][12];
                float wv[16] = {w0.x, w0.y, w0.z, w0.w, w1.x, w1.y, w1.z, w1.w,
                                w2.x, w2.y, w2.z, w2.w, w3.x, w3.y, w3.z, w3.w};
#pragma unroll
                for (int o = 0; o < 16; ++o) acc[o] = fmaf(v, wv[o], acc[o]);
            }
        }
    }
    if (active) {
        int yy = oty0 + ty, xx = otx0 + tx;
#pragma unroll
        for (int o = 0; o < 16; ++o) {
            float r = acc[o] + bias[ocb * 16 + o];
            out[(size_t)(ocb * 16 + o) * 8100 + yy * 90 + xx] =
                r > 0.f ? r : 0.f;
        }
    }
}

// ---------------------------------------------------------------------------
// 1x1 conv 128->256 + ReLU (writes neck channels 0..255)
// ---------------------------------------------------------------------------
__global__ __launch_bounds__(256) void conv1x1_relu_kernel(
    const float* __restrict__ in, const float* __restrict__ w,
    const float* __restrict__ bias, float* __restrict__ out)
{
    __shared__ float s_x[8][256];
    __shared__ float s_w[8][16];
    int p0 = blockIdx.x * 256; int ocb = blockIdx.y;
    int tid = threadIdx.x;
    float acc[16];
#pragma unroll
    for (int o = 0; o < 16; ++o) acc[o] = 0.f;

    for (int ic0 = 0; ic0 < 128; ic0 += 8) {
        for (int e = tid; e < 2048; e += 256) {
            int ic = e >> 8; int p = e & 255;
            s_x[ic][p] = (p0 + p < HW) ? in[(size_t)(ic0 + ic) * HW + p0 + p] : 0.f;
        }
        for (int e = tid; e < 128; e += 256) {
            int ic = e >> 4; int oc = e & 15;
            s_w[ic][oc] = w[(size_t)(ocb * 16 + oc) * 128 + ic0 + ic];
        }
        __syncthreads();
#pragma unroll
        for (int ic = 0; ic < 8; ++ic) {
            float v = s_x[ic][tid];
            float4 w0 = *(const float4*)&s_w[ic][0];
            float4 w1 = *(const float4*)&s_w[ic][4];
            float4 w2 = *(const float4*)&s_w[ic][8];
            float4 w3 = *(const float4*)&s_w[ic][12];
            float wv[16] = {w0.x, w0.y, w0.z, w0.w, w1.x, w1.y, w1.z, w1.w,
                            w2.x, w2.y, w2.z, w2.w, w3.x, w3.y, w3.z, w3.w};
#pragma unroll
            for (int o = 0; o < 16; ++o) acc[o] = fmaf(v, wv[o], acc[o]);
        }
        __syncthreads();
    }
    int p = p0 + tid;
    if (p < HW) {
#pragma unroll
        for (int o = 0; o < 16; ++o) {
            float r = acc[o] + bias[ocb * 16 + o];
            out[(size_t)(ocb * 16 + o) * HW + p] = r > 0.f ? r : 0.f;
        }
    }
}

// ---------------------------------------------------------------------------
// 2x2 stride-2 transposed conv + ReLU: x1[256][90][90] -> neck ch 256..511
// ---------------------------------------------------------------------------
__global__ __launch_bounds__(256) void deconv2x2_relu_kernel(
    const float* __restrict__ in, const float* __restrict__ wgt,
    const float* __restrict__ bias, float* __restrict__ out)
{
    __shared__ float s_x[8][256];
    __shared__ float s_w[8][4][16];
    int p0 = blockIdx.x * 256; int ocb = blockIdx.y;
    int tid = threadIdx.x;
    float acc[4][16];
#pragma unroll
    for (int ab = 0; ab < 4; ++ab)
#pragma unroll
        for (int o = 0; o < 16; ++o) acc[ab][o] = 0.f;

    for (int ic0 = 0; ic0 < 256; ic0 += 8) {
        for (int e = tid; e < 2048; e += 256) {
            int ic = e >> 8; int p = e & 255;
            s_x[ic][p] = (p0 + p < 8100) ? in[(size_t)(ic0 + ic) * 8100 + p0 + p] : 0.f;
        }
        for (int e = tid; e < 512; e += 256) {
            int oc = e & 15; int ab = (e >> 4) & 3; int ic = e >> 6;
            s_w[ic][ab][oc] =
                wgt[((size_t)(ocb * 16 + oc) * 256 + ic0 + ic) * 4 + ab];
        }
        __syncthreads();
#pragma unroll
        for (int ic = 0; ic < 8; ++ic) {
            float v = s_x[ic][tid];
#pragma unroll
            for (int ab = 0; ab < 4; ++ab) {
                float4 w0 = *(const float4*)&s_w[ic][ab][0];
                float4 w1 = *(const float4*)&s_w[ic][ab][4];
                float4 w2 = *(const float4*)&s_w[ic][ab][8];
                float4 w3 = *(const float4*)&s_w[ic][ab][12];
                float wv[16] = {w0.x, w0.y, w0.z, w0.w, w1.x, w1.y, w1.z, w1.w,
                                w2.x, w2.y, w2.z, w2.w, w3.x, w3.y, w3.z, w3.w};
#pragma unroll
                for (int o = 0; o < 16; ++o)
                    acc[ab][o] = fmaf(v, wv[o], acc[ab][o]);
            }
        }
        __syncthreads();
    }
    int sp = p0 + tid;
    if (sp < 8100) {
        int sy = sp / 90, sx = sp - sy * 90;
#pragma unroll
        for (int ab = 0; ab < 4; ++ab) {
            int a = ab >> 1, bb = ab & 1;
            int Y = 2 * sy + a, X = 2 * sx + bb;
#pragma unroll
            for (int o = 0; o < 16; ++o) {
                float r = acc[ab][o] + bias[ocb * 16 + o];
                out[(size_t)(ocb * 16 + o) * HW + Y * IMG + X] = r > 0.f ? r : 0.f;
            }
        }
    }
}

// ---------------------------------------------------------------------------
// Per-pixel 1x1 heads (12 outputs from 64 ch) + sigmoid on hm channels.
// ---------------------------------------------------------------------------
__global__ __launch_bounds__(256) void heads_kernel(
    const float* __restrict__ sh,
    const float* __restrict__ w_hm, const float* __restrict__ b_hm,
    const float* __restrict__ w_reg, const float* __restrict__ b_reg,
    const float* __restrict__ w_hei, const float* __restrict__ b_hei,
    const float* __restrict__ w_dim, const float* __restrict__ b_dim,
    const float* __restrict__ w_rot, const float* __restrict__ b_rot,
    const float* __restrict__ w_vel, const float* __restrict__ b_vel,
    float* __restrict__ hm_sig, float* __restrict__ heads)
{
    __shared__ float s_w[64][12];
    __shared__ float s_b[12];
    int t = blockIdx.y;
    int tid = threadIdx.x;
    for (int e = tid; e < 768; e += 256) {
        int c = e / 12; int r = e - c * 12;
        float v;
        if (r < 2)       v = w_hm [(t * 2 + r) * 64 + c];
        else if (r < 4)  v = w_reg[(t * 2 + r - 2) * 64 + c];
        else if (r < 5)  v = w_hei[t * 64 + c];
        else if (r < 8)  v = w_dim[(t * 3 + r - 5) * 64 + c];
        else if (r < 10) v = w_rot[(t * 2 + r - 8) * 64 + c];
        else             v = w_vel[(t * 2 + r - 10) * 64 + c];
        s_w[c][r] = v;
    }
    if (tid < 12) {
        int r = tid; float v;
        if (r < 2)       v = b_hm [t * 2 + r];
        else if (r < 4)  v = b_reg[t * 2 + r - 2];
        else if (r < 5)  v = b_hei[t];
        else if (r < 8)  v = b_dim[t * 3 + r - 5];
        else if (r < 10) v = b_rot[t * 2 + r - 8];
        else             v = b_vel[t * 2 + r - 10];
        s_b[r] = v;
    }
    __syncthreads();
    int p = blockIdx.x * 256 + tid;
    if (p >= HW) return;
    float a[12];
#pragma unroll
    for (int r = 0; r < 12; ++r) a[r] = 0.f;
    const float* shp = sh + (size_t)t * 64 * HW + p;
    for (int c = 0; c < 64; ++c) {
        float x = shp[(size_t)c * HW];
        float4 w0 = *(const float4*)&s_w[c][0];
        float4 w1 = *(const float4*)&s_w[c][4];
        float4 w2 = *(const float4*)&s_w[c][8];
        float wv[12] = {w0.x, w0.y, w0.z, w0.w, w1.x, w1.y, w1.z, w1.w,
                        w2.x, w2.y, w2.z, w2.w};
#pragma unroll
        for (int r = 0; r < 12; ++r) a[r] = fmaf(x, wv[r], a[r]);
    }
#pragma unroll
    for (int r = 0; r < 12; ++r) a[r] += s_b[r];
    hm_sig[(size_t)(t * 2 + 0) * HW + p] = 1.f / (1.f + expf(-a[0]));
    hm_sig[(size_t)(t * 2 + 1) * HW + p] = 1.f / (1.f + expf(-a[1]));
#pragma unroll
    for (int r = 0; r < 10; ++r)
        heads[(size_t)(t * 10 + r) * HW + p] = a[2 + r];
}

// ---------------------------------------------------------------------------
// 3x3 max-pool NMS -> packed sort keys (score_bits<<32 | ~combined_idx)
// ---------------------------------------------------------------------------
__global__ __launch_bounds__(256) void nms_key_kernel(
    const float* __restrict__ hm_sig, u64* __restrict__ keys)
{
    int t = blockIdx.y;
    int i = blockIdx.x * 256 + threadIdx.x;   // < 65536
    int nc = c_nc[t];
    u64 key = 0;
    if (i < nc * HW) {
        int c = i / HW; int p = i - c * HW;
        int y = p / IMG; int x = p - y * IMG;
        const float* base = hm_sig + (size_t)(t * 2 + c) * HW;
        float s = base[p];
        float m = s;
#pragma unroll
        for (int dy = -1; dy <= 1; ++dy)
#pragma unroll
            for (int dx = -1; dx <= 1; ++dx) {
                int yy = y + dy, xx = x + dx;
                if ((unsigned)yy < 180u && (unsigned)xx < 180u)
                    m = fmaxf(m, base[yy * IMG + xx]);
            }
        float sm = (s == m) ? s : 0.f;
        key = ((u64)__float_as_uint(sm) << 32) | (u64)(u32)(~(u32)i);
    }
    keys[(size_t)t * 65536 + i] = key;
}

// ---------------------------------------------------------------------------
// Bitonic sort (descending) of N u64 keys in LDS, T threads.
// ---------------------------------------------------------------------------
template <int N, int T>
__device__ void bitonic_sort_desc(u64* s)
{
    const int tid = threadIdx.x;
    for (int k = 2; k <= N; k <<= 1) {
        for (int j = k >> 1; j > 0; j >>= 1) {
            __syncthreads();
            for (int idx = tid; idx < N / 2; idx += T) {
                int i = ((idx & ~(j - 1)) << 1) | (idx & (j - 1));
                int l = i | j;
                u64 a = s[i], b = s[l];
                bool sw = ((i & k) == 0) ? (a < b) : (a > b);
                if (sw) { s[i] = b; s[l] = a; }
            }
        }
    }
    __syncthreads();
}

__global__ __launch_bounds__(256) void topk_stage1_kernel(
    const u64* __restrict__ keys, u64* __restrict__ cand)
{
    __shared__ u64 s[4096];
    int t = blockIdx.y, ch = blockIdx.x;
    const u64* src = keys + (size_t)t * 65536 + ch * 4096;
    for (int i = threadIdx.x; i < 4096; i += 256) s[i] = src[i];
    bitonic_sort_desc<4096, 256>(s);
    u64* dst = cand + ((size_t)t * 16 + ch) * 512;
    for (int i = threadIdx.x; i < 512; i += 256) dst[i] = s[i];
}

__global__ __launch_bounds__(512) void topk_stage2_kernel(
    const u64* __restrict__ cand, u64* __restrict__ top_keys)
{
    extern __shared__ u64 s2[];
    int t = blockIdx.x;
    for (int i = threadIdx.x; i < 8192; i += 512) s2[i] = cand[(size_t)t * 8192 + i];
    bitonic_sort_desc<8192, 512>(s2);
    for (int i = threadIdx.x; i < 500; i += 512) top_keys[t * 500 + i] = s2[i];
}

// ---------------------------------------------------------------------------
// Final top-300 over 3000 candidates + box decode.
// ---------------------------------------------------------------------------
__global__ __launch_bounds__(256) void final_decode_kernel(
    const u64* __restrict__ top_keys, const float* __restrict__ heads,
    float* __restrict__ qxyz, float* __restrict__ qpred)
{
    __shared__ u64 s[4096];
    int tid = threadIdx.x;
    for (int i = tid; i < 4096; i += 256) {
        u64 v = 0;
        if (i < 3000) {
            u64 k = top_keys[i];
            v = (k & 0xFFFFFFFF00000000ull) | (u64)(u32)(~(u32)i);
        }
        s[i] = v;
    }
    bitonic_sort_desc<4096, 256>(s);
    for (int q = tid; q < 300; q += 256) {
        u64 k2 = s[q];
        u32 gpos = ~(u32)(k2 & 0xFFFFFFFFull);
        int t = gpos / 500;
        u64 ok = top_keys[gpos];
        float score = __uint_as_float((u32)(ok >> 32));
        u32 comb = ~(u32)(ok & 0xFFFFFFFFull);
        int p = (int)(comb % HW);
        int yy = p / IMG, xx = p - yy * IMG;
        const float* hd = heads + (size_t)t * 10 * HW;
        float reg0 = hd[0 * HW + p], reg1 = hd[1 * HW + p], hei = hd[2 * HW + p];
        float d0 = expf(hd[3 * HW + p]);
        float d1 = expf(hd[4 * HW + p]);
        float d2 = expf(hd[5 * HW + p]);
        float rot0 = hd[6 * HW + p], rot1 = hd[7 * HW + p];
        float vel0 = hd[8 * HW + p], vel1 = hd[9 * HW + p];
        float yaw = atan2f(rot0, rot1);
        float X = ((float)xx + reg0) * 8.0f * 0.075f + (-54.0f);
        float Y = ((float)yy + reg1) * 8.0f * 0.075f + (-54.0f);
        qxyz[q * 3 + 0] = X;
        qxyz[q * 3 + 1] = Y;
        qxyz[q * 3 + 2] = hei;
        qpred[q * 7 + 0] = d0; qpred[q * 7 + 1] = d1; qpred[q * 7 + 2] = d2;
        qpred[q * 7 + 3] = yaw; qpred[q * 7 + 4] = vel0; qpred[q * 7 + 5] = vel1;
        qpred[q * 7 + 6] = score;
    }
}

// ---------------------------------------------------------------------------
// Bilinear grid sample of neck at 300 queries + positional embedding.
// ---------------------------------------------------------------------------
__global__ __launch_bounds__(256) void sample_embed_kernel(
    const float* __restrict__ neck, const float* __restrict__ qxyz,
    const float* __restrict__ qpred, float* __restrict__ qf,
    float* __restrict__ emb)
{
    int q = blockIdx.x;
    int tid = threadIdx.x;
    float X = qxyz[q * 3 + 0], Y = qxyz[q * 3 + 1];
    float xn = (X - (-54.0f)) / 108.0f * 2.0f - 1.0f;
    float yn = (Y - (-54.0f)) / 108.0f * 2.0f - 1.0f;
    float gx = (xn + 1.0f) * 180.0f / 2.0f - 0.5f;
    float gy = (yn + 1.0f) * 180.0f / 2.0f - 0.5f;
    float x0f = floorf(gx), y0f = floorf(gy);
    float wx = gx - x0f, wy = gy - y0f;
    int x0 = (int)x0f, y0 = (int)y0f;
    int xs[4] = {x0, x0 + 1, x0, x0 + 1};
    int ys[4] = {y0, y0, y0 + 1, y0 + 1};
    float wt[4] = {(1.f - wx) * (1.f - wy), wx * (1.f - wy),
                   (1.f - wx) * wy, wx * wy};
    int idx[4]; float wv[4];
#pragma unroll
    for (int k = 0; k < 4; ++k) {
        bool valid = xs[k] >= 0 && xs[k] < IMG && ys[k] >= 0 && ys[k] < IMG;
        int cx = xs[k] < 0 ? 0 : (xs[k] > IMG - 1 ? IMG - 1 : xs[k]);
        int cy = ys[k] < 0 ? 0 : (ys[k] > IMG - 1 ? IMG - 1 : ys[k]);
        idx[k] = cy * IMG + cx;
        wv[k] = valid ? wt[k] : 0.f;
    }
    for (int c = tid; c < 512; c += 256) {
        const float* f = neck + (size_t)c * HW;
        float v = f[idx[0]] * wv[0] + f[idx[1]] * wv[1] +
                  f[idx[2]] * wv[2] + f[idx[3]] * wv[3];
        qf[q * 512 + c] = v;
    }
    if (tid < 224) {
        int fidx = tid >> 5; int j = tid & 31; int m = j >> 1;
        float pos = qpred[q * 7 + fidx] * 6.283185307179586f;
        float dt = 2.0f * (float)m / 32.0f + 1.0f;
        float v = pos / dt;
        emb[q * 224 + tid] = (j & 1) ? cosf(v) : sinf(v);
    }
}

// ---------------------------------------------------------------------------
// qf_out = qf @ w_qe^T + b_qe + qf + emb @ w_qpe^T + b_qpe
// ---------------------------------------------------------------------------
__global__ __launch_bounds__(256) void qfout_kernel(
    const float* __restrict__ qf, const float* __restrict__ emb,
    const float* __restrict__ w_qe, const float* __restrict__ b_qe,
    const float* __restrict__ w_qpe, const float* __restrict__ b_qpe,
    float* __restrict__ outq)
{
    int g = blockIdx.x * 256 + threadIdx.x;
    if (g >= 300 * 512) return;
    int q = g >> 9, o = g & 511;
    const float* qrow = qf + q * 512;
    const float* wrow = w_qe + (size_t)o * 512;
    float acc = 0.f;
    for (int c = 0; c < 512; ++c) acc = fmaf(qrow[c], wrow[c], acc);
    const float* erow = emb + q * 224;
    const float* wr2 = w_qpe + (size_t)o * 224;
    float acc2 = 0.f;
    for (int j = 0; j < 224; ++j) acc2 = fmaf(erow[j], wr2[j], acc2);
    outq[g] = acc + b_qe[o] + qrow[o] + acc2 + b_qpe[o];
}

// ---------------------------------------------------------------------------
// bev_out[p][o] = sum_c neck[c][p] * w_pre[o][c] + b_pre[o] + neck[o][p]
// ---------------------------------------------------------------------------
__global__ __launch_bounds__(256) void bev_out_kernel(
    const float* __restrict__ neck, const float* __restrict__ w_pre,
    const float* __restrict__ b_pre, float* __restrict__ outb)
{
    __shared__ float sA[16][132];
    __shared__ float sB[16][132];
    int per = gridDim.x >> 3;
    int g = (blockIdx.x & 7) * per + (blockIdx.x >> 3);
    int pt = g >> 2; int ob = g & 3;
    int p0 = pt * 128, o0 = ob * 128;
    int tid = threadIdx.x, tx = tid & 15, ty = tid >> 4;
    float acc[8][8];
#pragma unroll
    for (int i = 0; i < 8; ++i)
#pragma unroll
        for (int j = 0; j < 8; ++j) acc[i][j] = 0.f;

    for (int c0 = 0; c0 < 512; c0 += 16) {
        for (int e = tid; e < 2048; e += 256) {
            int k = e >> 7, p = e & 127;
            int gp = p0 + p;
            sA[k][p] = gp < HW ? neck[(size_t)(c0 + k) * HW + gp] : 0.f;
        }
        for (int e4 = tid; e4 < 512; e4 += 256) {
            int o = e4 >> 2, kk = e4 & 3;
            float4 v = *(const float4*)&w_pre[(size_t)(o0 + o) * 512 + c0 + kk * 4];
            sB[kk * 4 + 0][o] = v.x; sB[kk * 4 + 1][o] = v.y;
            sB[kk * 4 + 2][o] = v.z; sB[kk * 4 + 3][o] = v.w;
        }
        __syncthreads();
#pragma unroll
        for (int k = 0; k < 16; ++k) {
            float4 a0 = *(const float4*)&sA[k][ty * 4];
            float4 a1 = *(const float4*)&sA[k][64 + ty * 4];
            float4 b0 = *(const float4*)&sB[k][tx * 4];
            float4 b1 = *(const float4*)&sB[k][64 + tx * 4];
            float av[8] = {a0.x, a0.y, a0.z, a0.w, a1.x, a1.y, a1.z, a1.w};
            float bv[8] = {b0.x, b0.y, b0.z, b0.w, b1.x, b1.y, b1.z, b1.w};
#pragma unroll
            for (int i = 0; i < 8; ++i)
#pragma unroll
                for (int j = 0; j < 8; ++j)
                    acc[i][j] = fmaf(av[i], bv[j], acc[i][j]);
        }
        __syncthreads();
    }
#pragma unroll
    for (int i = 0; i < 8; ++i) {
        int pl = (i < 4) ? (ty * 4 + i) : (64 + ty * 4 + i - 4);
        int p = p0 + pl;
        if (p >= HW) continue;
#pragma unroll
        for (int j = 0; j < 8; ++j) {
            int ol = (j < 4) ? (tx * 4 + j) : (64 + tx * 4 + j - 4);
            int o = o0 + ol;
            outb[(size_t)p * 512 + o] =
                acc[i][j] + b_pre[o] + neck[(size_t)o * HW + p];
        }
    }
}

// ---------------------------------------------------------------------------
extern "C" void kernel_launch(void* const* d_in, const int* in_sizes, int n_in,
                              void* d_out, int out_size, void* d_ws, size_t ws_size,
                              hipStream_t stream)
{
    (void)in_sizes; (void)n_in; (void)out_size; (void)ws_size;

    const float* bev   = (const float*)d_in[0];
    const float* w_b0  = (const float*)d_in[1];
    const float* b_b0  = (const float*)d_in[2];
    const float* w_b1  = (const float*)d_in[3];
    const float* b_b1  = (const float*)d_in[4];
    const float* w_n0  = (const float*)d_in[5];
    const float* b_n0  = (const float*)d_in[6];
    const float* w_n1  = (const float*)d_in[7];
    const float* b_n1  = (const float*)d_in[8];
    const float* w_sh  = (const float*)d_in[9];
    const float* b_sh  = (const float*)d_in[10];
    const float* w_hm  = (const float*)d_in[11];
    const float* b_hm  = (const float*)d_in[12];
    const float* w_reg = (const float*)d_in[13];
    const float* b_reg = (const float*)d_in[14];
    const float* w_hei = (const float*)d_in[15];
    const float* b_hei = (const float*)d_in[16];
    const float* w_dim = (const float*)d_in[17];
    const float* b_dim = (const float*)d_in[18];
    const float* w_rot = (const float*)d_in[19];
    const float* b_rot = (const float*)d_in[20];
    const float* w_vel = (const float*)d_in[21];
    const float* b_vel = (const float*)d_in[22];
    const float* w_pre = (const float*)d_in[23];
    const float* b_pre = (const float*)d_in[24];
    const float* w_qe  = (const float*)d_in[25];
    const float* b_qe  = (const float*)d_in[26];
    const float* w_qpe = (const float*)d_in[27];
    const float* b_qpe = (const float*)d_in[28];

    float* out = (float*)d_out;
    float* wsf = (float*)d_ws;

    float* x0    = wsf;
    float* x1    = x0 + (size_t)128 * HW;
    float* neck  = x1 + (size_t)256 * 8100;
    float* sh    = neck + (size_t)512 * HW;
    float* heads = sh + (size_t)NTASK * 64 * HW;
    float* hm    = heads + (size_t)NTASK * 10 * HW;
    float* qpred = hm + (size_t)NTASK * 2 * HW;
    float* qf    = qpred + 300 * 7;
    float* emb   = qf + 300 * 512;
    u64* keys    = (u64*)(emb + 300 * 224);
    u64* cand    = keys + (size_t)NTASK * 65536;
    u64* topk    = cand + (size_t)NTASK * 16 * 512;
    float* zp    = (float*)(((uintptr_t)(topk + 3008) + 63) & ~(uintptr_t)63);

    float* out_bev = out;
    float* out_qf  = out + (size_t)HW * 512;
    float* out_xyz = out + (size_t)HW * 512 + 300 * 512;

    zp_init_kernel<<<dim3(1), dim3(64), 0, stream>>>(zp);

    // block0: 256->128, n_ocb = 8 (16 oc each), grid 288 (div by 8)
    conv3x3_relu_v21<<<dim3(288), dim3(512), 0, stream>>>(
        bev, w_b0, b_b0, x0, zp, 256, 8);
    conv3x3s2_relu_v2<<<dim3(36, 16), dim3(256), 0, stream>>>(
        x0, w_b1, b_b1, x1);
    conv1x1_relu_kernel<<<dim3(127, 16), dim3(256), 0, stream>>>(
        x0, w_n0, b_n0, neck);
    deconv2x2_relu_kernel<<<dim3(32, 16), dim3(256), 0, stream>>>(
        x1, w_n1, b_n1, neck + (size_t)256 * HW);
    // shared heads: 512->384 (6 tasks x 64 oc folded), n_ocb = 24, grid 864
    conv3x3_relu_v21<<<dim3(864), dim3(512), 0, stream>>>(
        neck, w_sh, b_sh, sh, zp, 512, 24);
    heads_kernel<<<dim3(127, 6), dim3(256), 0, stream>>>(
        sh, w_hm, b_hm, w_reg, b_reg, w_hei, b_hei, w_dim, b_dim,
        w_rot, b_rot, w_vel, b_vel, hm, heads);
    nms_key_kernel<<<dim3(256, 6), dim3(256), 0, stream>>>(hm, keys);
    topk_stage1_kernel<<<dim3(16, 6), dim3(256), 0, stream>>>(keys, cand);
    topk_stage2_kernel<<<dim3(6), dim3(512), 65536, stream>>>(cand, topk);
    final_decode_kernel<<<dim3(1), dim3(256), 0, stream>>>(
        topk, heads, out_xyz, qpred);
    sample_embed_kernel<<<dim3(300), dim3(256), 0, stream>>>(
        neck, out_xyz, qpred, qf, emb);
    qfout_kernel<<<dim3(600), dim3(256), 0, stream>>>(
        qf, emb, w_qe, b_qe, w_qpe, b_qpe, out_qf);
    bev_out_kernel<<<dim3(1016), dim3(256), 0, stream>>>(
        neck, w_pre, b_pre, out_bev);
}